// Round 3
// baseline (6178.458 us; speedup 1.0000x reference)
//
#include <hip/hip_runtime.h>
#include <math.h>

typedef __bf16 bf16x8 __attribute__((ext_vector_type(8)));
typedef float f32x4 __attribute__((ext_vector_type(4)));
typedef unsigned long long u64;

#define HD 512
#define NB 128
#define NI 32
#define NL 96
#define NS 16
#define NF 24
#define NSTEP 23
#define TS 40   // padded LDS transpose stride (shorts)

#define MFMA16(a,b,c) __builtin_amdgcn_mfma_f32_16x16x32_bf16(a,b,c,0,0,0)

__device__ __forceinline__ unsigned short f2bf(float f) {
    union { float f; unsigned u; } v; v.f = f;
    unsigned r = v.u + 0x7fffu + ((v.u >> 16) & 1u);
    return (unsigned short)(r >> 16);
}
__device__ __forceinline__ float bf2f(unsigned short h) {
    union { unsigned u; float f; } v; v.u = ((unsigned)h) << 16;
    return v.f;
}
__device__ __forceinline__ void split_bf(float v, unsigned short& hi, unsigned short& lo) {
    unsigned short h = f2bf(v);
    hi = h;
    lo = f2bf(v - bf2f(h));
}
__device__ __forceinline__ float sigm(float x) { return 1.0f / (1.0f + __expf(-x)); }
__device__ __forceinline__ float softp(float x) {
    return fmaxf(x, 0.0f) + log1pf(__expf(-fabsf(x)));
}
__device__ __forceinline__ bf16x8 ld8(const unsigned short* p) {
    return *reinterpret_cast<const bf16x8*>(p);
}
__device__ __forceinline__ f32x4 mfma3(bf16x8 ahi, bf16x8 alo, const unsigned short* bp, f32x4 c) {
    bf16x8 bhi = ld8(bp);
    bf16x8 blo = ld8(bp + 8);
    c = MFMA16(ahi, bhi, c);
    c = MFMA16(alo, bhi, c);
    c = MFMA16(ahi, blo, c);
    return c;
}

// ---- device-coherent state exchange: relaxed agent-scope 8B atomics ----
// SoA tile layout: a 64-lane fragment tile is 4 planes of [64] u64.
__device__ __forceinline__ void st_frag(u64* tile, int lane, bf16x8 hi, bf16x8 lo) {
    union { bf16x8 v; u64 q[2]; } h, l;
    h.v = hi; l.v = lo;
    __hip_atomic_store(tile + 0 * 64 + lane, h.q[0], __ATOMIC_RELAXED, __HIP_MEMORY_SCOPE_AGENT);
    __hip_atomic_store(tile + 1 * 64 + lane, h.q[1], __ATOMIC_RELAXED, __HIP_MEMORY_SCOPE_AGENT);
    __hip_atomic_store(tile + 2 * 64 + lane, l.q[0], __ATOMIC_RELAXED, __HIP_MEMORY_SCOPE_AGENT);
    __hip_atomic_store(tile + 3 * 64 + lane, l.q[1], __ATOMIC_RELAXED, __HIP_MEMORY_SCOPE_AGENT);
}
// batched tile load: issue 4 independent coherent loads into registers, no use yet.
__device__ __forceinline__ void ld_q(const u64* tile, int lane, u64* q) {
    q[0] = __hip_atomic_load(tile + 0 * 64 + lane, __ATOMIC_RELAXED, __HIP_MEMORY_SCOPE_AGENT);
    q[1] = __hip_atomic_load(tile + 1 * 64 + lane, __ATOMIC_RELAXED, __HIP_MEMORY_SCOPE_AGENT);
    q[2] = __hip_atomic_load(tile + 2 * 64 + lane, __ATOMIC_RELAXED, __HIP_MEMORY_SCOPE_AGENT);
    q[3] = __hip_atomic_load(tile + 3 * 64 + lane, __ATOMIC_RELAXED, __HIP_MEMORY_SCOPE_AGENT);
}
__device__ __forceinline__ void q2f(const u64* q, bf16x8& hi, bf16x8& lo) {
    union { bf16x8 v; u64 w[2]; } h, l;
    h.w[0] = q[0]; h.w[1] = q[1]; l.w[0] = q[2]; l.w[1] = q[3];
    hi = h.v; lo = l.v;
}

// barrier: drain own vmem, block-barrier, relaxed counter RMW, SINGLE thread spins.
// No __threadfence -> no L2 writeback/invalidate -> weights stay L2-resident.
// (Round-1 lesson: multi-wave flag polling floods the fabric with coherent loads.)
__device__ __forceinline__ void gbar(unsigned* ctr, unsigned target) {
    __builtin_amdgcn_s_waitcnt(0);
    __syncthreads();
    if (threadIdx.x == 0) {
        __hip_atomic_fetch_add(ctr, 1u, __ATOMIC_RELAXED, __HIP_MEMORY_SCOPE_AGENT);
        while (__hip_atomic_load(ctr, __ATOMIC_RELAXED, __HIP_MEMORY_SCOPE_AGENT) < target)
            __builtin_amdgcn_s_sleep(2);
    }
    __syncthreads();
}

// ---------- prep: pack W[N][K] fp32 -> split bf16 B-fragments ----------
__global__ void pack_w(const float* __restrict__ W, unsigned short* __restrict__ Wp,
                       int N, int K) {
    int idx = blockIdx.x * 256 + threadIdx.x;
    int total = (N / 16) * (K / 32) * 64;
    if (idx >= total) return;
    int lane = idx & 63;
    int t2 = idx >> 6;
    int KT = K / 32;
    int kt = t2 % KT, nt = t2 / KT;
    const float* src = W + (size_t)(nt * 16 + (lane & 15)) * K + kt * 32 + (lane >> 4) * 8;
    unsigned short* dst = Wp + (size_t)idx * 16;
    #pragma unroll
    for (int j = 0; j < 8; ++j) split_bf(src[j], dst[j], dst[8 + j]);
}

// ---------- prep: x[B][I][L] fp32 -> xhi/xlo [L][B][I] bf16 ----------
__global__ void pack_x(const float* __restrict__ x, unsigned short* __restrict__ xhi,
                       unsigned short* __restrict__ xlo) {
    int idx = blockIdx.x * 256 + threadIdx.x;
    if (idx >= NL * NB) return;
    int b = idx % NB, l = idx / NB;
    size_t base = (size_t)(l * NB + b) * NI;
    #pragma unroll
    for (int i = 0; i < NI; ++i)
        split_bf(x[((size_t)b * NI + i) * NL + l], xhi[base + i], xlo[base + i]);
}

// =================== fused cooperative kernel ===================
// __launch_bounds__(512, 2): grid is fixed at 1 block/CU (256 coop blocks) = 8
// waves/block = 2 waves/SIMD. Declaring exactly that raises the VGPR cap from
// 128 to 256 -- rounds 1-2 spilled the 128-VGPR q arrays to scratch at the
// default cap (VGPR_Count pinned at 128, FETCH_SIZE 0.78 -> 8.7 GB).
__global__ __launch_bounds__(512, 2) void coop_all(
    const unsigned short* __restrict__ xhi, const unsigned short* __restrict__ xlo,
    const unsigned short* __restrict__ wih_p, const unsigned short* __restrict__ whh_p,
    const unsigned short* __restrict__ w1_p, const unsigned short* __restrict__ w2_p,
    const unsigned short* __restrict__ gw_p, const unsigned short* __restrict__ dwhh_p,
    const unsigned short* __restrict__ outw_p,
    const float* __restrict__ ebih, const float* __restrict__ ebhh,
    const float* __restrict__ fb1, const float* __restrict__ fb2,
    const float* __restrict__ gb, const float* __restrict__ dbih,
    const float* __restrict__ dbhh, const float* __restrict__ outb,
    const float* __restrict__ noise,
    u64* hE0, u64* hE1, u64* hP0, u64* hP1, u64* uP,
    unsigned* h_encF, float* out, unsigned* bar)
{
    const int bid = blockIdx.x;
    const int tid = threadIdx.x, lane = tid & 63, wv = tid >> 6;
    const int l15 = lane & 15, g4 = lane >> 4;
    const f32x4 zz = {0.f, 0.f, 0.f, 0.f};

    __shared__ float pred[4][8][16][16];
    __shared__ __align__(16) unsigned short Thi[128][TS];
    __shared__ __align__(16) unsigned short Tlo[128][TS];

    // =============== encoder: group g = m-tile (16 rows), slice n = 16 units ===============
    {
        const int g = bid & 7, n = bid >> 3;
        unsigned* ctr = bar + (1 + g) * 16;
        float hcell = 0.f;
        float cr = 0.f, cz = 0.f, binx = 0.f, bhnn = 0.f;
        const int crow = tid >> 4, cunit = tid & 15;
        if (tid < 256) {
            int u = n * 16 + cunit;
            cr = ebih[u] + ebhh[u];
            cz = ebih[HD + u] + ebhh[HD + u];
            binx = ebih[2 * HD + u];
            bhnn = ebhh[2 * HD + u];
        }
        u64* hEbuf[2] = {hE0, hE1};
        #pragma unroll 1
        for (int l = 0; l < NL; ++l) {
            const u64* curb = hEbuf[l & 1];
            u64* nxt = hEbuf[(l & 1) ^ 1];
            // issue x loads first (read-only input, HBM/L2)
            bf16x8 axh, axl;
            if (wv == 0) {
                size_t xb = (size_t)(l * NB + g * 16 + l15) * NI + g4 * 8;
                axh = ld8(xhi + xb);
                axl = ld8(xlo + xb);
            }
            // batch both state-tile loads (8x 8B fabric loads) before any MFMA
            u64 q0[4], q1[4];
            ld_q(curb + (size_t)(g * 16 + wv * 2 + 0) * 256, lane, q0);
            ld_q(curb + (size_t)(g * 16 + wv * 2 + 1) * 256, lane, q1);
            f32x4 pr = zz, pz = zz, pnh = zz, pnx = zz;
            if (wv == 0) {
                pr  = mfma3(axh, axl, wih_p + ((size_t)(0 * 32 + n) * 64 + lane) * 16, pr);
                pz  = mfma3(axh, axl, wih_p + ((size_t)(1 * 32 + n) * 64 + lane) * 16, pz);
                pnx = mfma3(axh, axl, wih_p + ((size_t)(2 * 32 + n) * 64 + lane) * 16, pnx);
            }
            #pragma unroll
            for (int kk = 0; kk < 2; ++kk) {
                int kt = wv * 2 + kk;
                bf16x8 ah, al;
                q2f(kk ? q1 : q0, ah, al);
                pr  = mfma3(ah, al, whh_p + ((size_t)((0 * 32 + n) * 16 + kt) * 64 + lane) * 16, pr);
                pz  = mfma3(ah, al, whh_p + ((size_t)((1 * 32 + n) * 16 + kt) * 64 + lane) * 16, pz);
                pnh = mfma3(ah, al, whh_p + ((size_t)((2 * 32 + n) * 16 + kt) * 64 + lane) * 16, pnh);
            }
            #pragma unroll
            for (int v = 0; v < 4; ++v) {
                pred[0][wv][g4 * 4 + v][l15] = pr[v];
                pred[1][wv][g4 * 4 + v][l15] = pz[v];
                pred[2][wv][g4 * 4 + v][l15] = pnh[v];
                if (wv == 0) pred[3][0][g4 * 4 + v][l15] = pnx[v];
            }
            __syncthreads();
            if (tid < 256) {
                float ar = 0.f, az = 0.f, anh_ = 0.f;
                #pragma unroll
                for (int w = 0; w < 8; ++w) {
                    ar += pred[0][w][crow][cunit];
                    az += pred[1][w][crow][cunit];
                    anh_ += pred[2][w][crow][cunit];
                }
                float anx_ = pred[3][0][crow][cunit];
                float r = sigm(ar + cr);
                float z = sigm(az + cz);
                float nn = tanhf(anx_ + binx + r * (anh_ + bhnn));
                hcell = (1.f - z) * nn + z * hcell;
                unsigned short hi, lo;
                split_bf(hcell, hi, lo);
                Thi[crow][cunit] = hi;
                Tlo[crow][cunit] = lo;
                if (l == NL - 1)
                    __hip_atomic_store(h_encF + (size_t)(g * 16 + crow) * HD + n * 16 + cunit,
                                       __float_as_uint(hcell),
                                       __ATOMIC_RELAXED, __HIP_MEMORY_SCOPE_AGENT);
            }
            __syncthreads();
            if (tid < 32) {
                int half = n & 1, kt = n >> 1;
                int lp = half * 32 + tid;
                bf16x8 vh = *(const bf16x8*)&Thi[tid & 15][(tid >> 4) * 8];
                bf16x8 vl = *(const bf16x8*)&Tlo[tid & 15][(tid >> 4) * 8];
                st_frag(nxt + (size_t)(g * 16 + kt) * 256, lp, vh, vl);
            }
            gbar(ctr, 32u * (l + 1));
        }
    }

    // full-grid barrier: h_encF + final frags (hE0) visible
    gbar(bar, 256u);

    // =============== SDE + decoder: group g2 = sample (128 rows), slice n2 = 32 units ===============
    const int g2 = (bid & 7) * 2 + ((bid >> 3) & 1);
    const int n2 = bid >> 4;
    unsigned* ctr2 = bar + (9 + g2) * 16;
    const float dt = (float)NF / (float)NSTEP;
    const float sqdt = sqrtf(dt);

    float hreg[2][4];
    #pragma unroll
    for (int nt = 0; nt < 2; ++nt)
        #pragma unroll
        for (int v = 0; v < 4; ++v)
            hreg[nt][v] = __uint_as_float(__hip_atomic_load(
                h_encF + (size_t)(wv * 16 + g4 * 4 + v) * HD + n2 * 32 + nt * 16 + l15,
                __ATOMIC_RELAXED, __HIP_MEMORY_SCOPE_AGENT));

    float b1v[2], b2v[2], gbv[2];
    #pragma unroll
    for (int nt = 0; nt < 2; ++nt) {
        int u = n2 * 32 + nt * 16 + l15;
        b1v[nt] = fb1[u]; b2v[nt] = fb2[u]; gbv[nt] = gb[u];
    }

    u64* hPb[2] = {hP0, hP1};
    int cur = 0;

    #pragma unroll 1
    for (int st = 0; st < NSTEP; ++st) {
        u64 qa[8][4], qb[8][4];
        // ---- phase A: u = tanh(h W1^T + b1)  AND  g-pre = h gW^T ----
        const u64* hsrc = (st == 0) ? hE0 : hPb[cur];
        const size_t mtb = (size_t)((st == 0) ? (wv * 16) : ((g2 * 8 + wv) * 16));
        // batch all 64 coherent state loads before any MFMA (one fabric round trip)
        #pragma unroll
        for (int kk = 0; kk < 8; ++kk) ld_q(hsrc + (mtb + kk) * 256, lane, qa[kk]);
        #pragma unroll
        for (int kk = 0; kk < 8; ++kk) ld_q(hsrc + (mtb + 8 + kk) * 256, lane, qb[kk]);
        // noise is phase-B input but flag-independent: issue now, consume after next gbar
        float nz[2][4];
        #pragma unroll
        for (int nt = 0; nt < 2; ++nt)
            #pragma unroll
            for (int v = 0; v < 4; ++v)
                nz[nt][v] = noise[((size_t)(g2 * NSTEP + st) * NB + (wv * 16 + g4 * 4 + v)) * HD
                                  + n2 * 32 + nt * 16 + l15];
        f32x4 au[2] = {zz, zz}, ag[2] = {zz, zz};
        #pragma unroll
        for (int kk = 0; kk < 16; ++kk) {
            bf16x8 ah, al;
            q2f(kk < 8 ? qa[kk] : qb[kk - 8], ah, al);
            #pragma unroll
            for (int nt = 0; nt < 2; ++nt) {
                au[nt] = mfma3(ah, al, w1_p + ((size_t)((n2 * 2 + nt) * 16 + kk) * 64 + lane) * 16, au[nt]);
                ag[nt] = mfma3(ah, al, gw_p + ((size_t)((n2 * 2 + nt) * 16 + kk) * 64 + lane) * 16, ag[nt]);
            }
        }
        #pragma unroll
        for (int nt = 0; nt < 2; ++nt)
            #pragma unroll
            for (int v = 0; v < 4; ++v) {
                unsigned short hi, lo;
                split_bf(tanhf(au[nt][v] + b1v[nt]), hi, lo);
                Thi[wv * 16 + g4 * 4 + v][nt * 16 + l15] = hi;
                Tlo[wv * 16 + g4 * 4 + v][nt * 16 + l15] = lo;
            }
        __syncthreads();
        {
            int mt = tid >> 6, ln = tid & 63;
            bf16x8 vh = *(const bf16x8*)&Thi[mt * 16 + (ln & 15)][(ln >> 4) * 8];
            bf16x8 vl = *(const bf16x8*)&Tlo[mt * 16 + (ln & 15)][(ln >> 4) * 8];
            st_frag(uP + (size_t)((g2 * 8 + mt) * 16 + n2) * 256, ln, vh, vl);
        }
        gbar(ctr2, 16u * (2 * st + 1));

        // ---- phase B: f = u W2^T + b2 ----
        #pragma unroll
        for (int kk = 0; kk < 8; ++kk)
            ld_q(uP + (size_t)((g2 * 8 + wv) * 16 + kk) * 256, lane, qa[kk]);
        #pragma unroll
        for (int kk = 0; kk < 8; ++kk)
            ld_q(uP + (size_t)((g2 * 8 + wv) * 16 + 8 + kk) * 256, lane, qb[kk]);
        f32x4 af[2] = {zz, zz};
        #pragma unroll
        for (int kk = 0; kk < 16; ++kk) {
            bf16x8 uh, ul;
            q2f(kk < 8 ? qa[kk] : qb[kk - 8], uh, ul);
            #pragma unroll
            for (int nt = 0; nt < 2; ++nt)
                af[nt] = mfma3(uh, ul, w2_p + ((size_t)((n2 * 2 + nt) * 16 + kk) * 64 + lane) * 16, af[nt]);
        }
        #pragma unroll
        for (int nt = 0; nt < 2; ++nt)
            #pragma unroll
            for (int v = 0; v < 4; ++v) {
                int b = wv * 16 + g4 * 4 + v;
                float f = af[nt][v] + b2v[nt];
                float gg = softp(ag[nt][v] + gbv[nt]);
                hreg[nt][v] += f * dt + gg * sqdt * nz[nt][v];
                unsigned short hi, lo;
                split_bf(hreg[nt][v], hi, lo);
                Thi[b][nt * 16 + l15] = hi;
                Tlo[b][nt * 16 + l15] = lo;
            }
        __syncthreads();
        {
            int mt = tid >> 6, ln = tid & 63;
            bf16x8 vh = *(const bf16x8*)&Thi[mt * 16 + (ln & 15)][(ln >> 4) * 8];
            bf16x8 vl = *(const bf16x8*)&Tlo[mt * 16 + (ln & 15)][(ln >> 4) * 8];
            st_frag(hPb[cur ^ 1] + (size_t)((g2 * 8 + mt) * 16 + n2) * 256, ln, vh, vl);
        }
        cur ^= 1;
        gbar(ctr2, 16u * (2 * st + 2));
    }

    // =============== decoder GRU + out-proj ===============
    float crv[2], czv[2], binv[2], bhnv[2];
    #pragma unroll
    for (int nt = 0; nt < 2; ++nt) {
        int u = n2 * 32 + nt * 16 + l15;
        crv[nt] = dbih[u] + dbhh[u];
        czv[nt] = dbih[HD + u] + dbhh[HD + u];
        binv[nt] = dbih[2 * HD + u];
        bhnv[nt] = dbhh[2 * HD + u];
    }
    const float obias = (n2 < 2) ? outb[n2 * 16 + l15] : 0.f;

    #pragma unroll 1
    for (int j = 0; j <= NF; ++j) {
        const u64* hsrc = hPb[cur];
        u64 qa[8][4], qb[8][4];
        if (j < NF || n2 < 2) {
            #pragma unroll
            for (int kk = 0; kk < 8; ++kk)
                ld_q(hsrc + (size_t)((g2 * 8 + wv) * 16 + kk) * 256, lane, qa[kk]);
            #pragma unroll
            for (int kk = 0; kk < 8; ++kk)
                ld_q(hsrc + (size_t)((g2 * 8 + wv) * 16 + 8 + kk) * 256, lane, qb[kk]);
        }
        if (j >= 1 && n2 < 2) {
            f32x4 ao = zz;
            #pragma unroll
            for (int kk = 0; kk < 16; ++kk) {
                bf16x8 ah, al;
                q2f(kk < 8 ? qa[kk] : qb[kk - 8], ah, al);
                ao = mfma3(ah, al, outw_p + ((size_t)(n2 * 16 + kk) * 64 + lane) * 16, ao);
            }
            #pragma unroll
            for (int v = 0; v < 4; ++v) {
                int b = wv * 16 + g4 * 4 + v;
                out[(((size_t)g2 * NB + b) * NI + (n2 * 16 + l15)) * NF + (j - 1)] = ao[v] + obias;
            }
        }
        if (j == NF) break;   // final out-proj done; no further reads/writes -> no barrier
        // per-nt pass keeps accumulator pressure low while q tiles stay resident
        #pragma unroll
        for (int nt = 0; nt < 2; ++nt) {
            int nn = n2 * 2 + nt;
            f32x4 ar = zz, az2 = zz, anh = zz;
            #pragma unroll
            for (int kk = 0; kk < 16; ++kk) {
                bf16x8 ah, al;
                q2f(kk < 8 ? qa[kk] : qb[kk - 8], ah, al);
                ar  = mfma3(ah, al, dwhh_p + ((size_t)((0 * 32 + nn) * 16 + kk) * 64 + lane) * 16, ar);
                az2 = mfma3(ah, al, dwhh_p + ((size_t)((1 * 32 + nn) * 16 + kk) * 64 + lane) * 16, az2);
                anh = mfma3(ah, al, dwhh_p + ((size_t)((2 * 32 + nn) * 16 + kk) * 64 + lane) * 16, anh);
            }
            #pragma unroll
            for (int v = 0; v < 4; ++v) {
                int b = wv * 16 + g4 * 4 + v;
                float r = sigm(ar[v] + crv[nt]);
                float z = sigm(az2[v] + czv[nt]);
                float nn2 = tanhf(binv[nt] + r * (anh[v] + bhnv[nt]));
                hreg[nt][v] = (1.f - z) * nn2 + z * hreg[nt][v];
                unsigned short hi, lo;
                split_bf(hreg[nt][v], hi, lo);
                Thi[b][nt * 16 + l15] = hi;
                Tlo[b][nt * 16 + l15] = lo;
            }
        }
        __syncthreads();
        {
            int mt = tid >> 6, ln = tid & 63;
            bf16x8 vh = *(const bf16x8*)&Thi[mt * 16 + (ln & 15)][(ln >> 4) * 8];
            bf16x8 vl = *(const bf16x8*)&Tlo[mt * 16 + (ln & 15)][(ln >> 4) * 8];
            st_frag(hPb[cur ^ 1] + (size_t)((g2 * 8 + mt) * 16 + n2) * 256, ln, vh, vl);
        }
        cur ^= 1;
        gbar(ctr2, 16u * (2 * NSTEP + j + 1));
    }
}

extern "C" void kernel_launch(void* const* d_in, const int* in_sizes, int n_in,
                              void* d_out, int out_size, void* d_ws, size_t ws_size,
                              hipStream_t stream) {
    const float* x       = (const float*)d_in[0];
    const float* noise   = (const float*)d_in[1];
    const float* enc_Wih = (const float*)d_in[2];
    const float* enc_Whh = (const float*)d_in[3];
    const float* enc_bih = (const float*)d_in[4];
    const float* enc_bhh = (const float*)d_in[5];
    const float* f_W1    = (const float*)d_in[6];
    const float* f_b1    = (const float*)d_in[7];
    const float* f_W2    = (const float*)d_in[8];
    const float* f_b2    = (const float*)d_in[9];
    const float* g_W     = (const float*)d_in[10];
    const float* g_b     = (const float*)d_in[11];
    const float* dec_Whh = (const float*)d_in[13];
    const float* dec_bih = (const float*)d_in[14];
    const float* dec_bhh = (const float*)d_in[15];
    const float* out_W   = (const float*)d_in[16];
    const float* out_b   = (const float*)d_in[17];
    float* out = (float*)d_out;

    char* ws = (char*)d_ws;
    unsigned short* whh_p  = (unsigned short*)(ws + 0);          // 3 MB
    unsigned short* wih_p  = (unsigned short*)(ws + 3145728);    // 192 KB
    unsigned short* w1_p   = (unsigned short*)(ws + 3342336);    // 1 MB
    unsigned short* w2_p   = (unsigned short*)(ws + 4390912);    // 1 MB
    unsigned short* gw_p   = (unsigned short*)(ws + 5439488);    // 1 MB
    unsigned short* dwhh_p = (unsigned short*)(ws + 6488064);    // 3 MB
    unsigned short* outw_p = (unsigned short*)(ws + 9633792);    // 64 KB
    unsigned short* xhi    = (unsigned short*)(ws + 9699328);    // 768 KB
    unsigned short* xlo    = (unsigned short*)(ws + 10485760);   // 768 KB
    u64*            hE1    = (u64*)(ws + 11272192);              // 256 KB
    u64*            hP0    = (u64*)(ws + 11534336);              // 4 MB
    u64*            hP1    = (u64*)(ws + 15728640);              // 4 MB
    u64*            uP     = (u64*)(ws + 19922944);              // 4 MB
    unsigned*       h_encF = (unsigned*)(ws + 24117248);         // 256 KB
    unsigned*       bar    = (unsigned*)(ws + 24379392);         // 2 KB
    u64*            hE0    = (u64*)(ws + 24381440);              // 256 KB (contiguous w/ bar)

    // zero barrier counters + initial encoder h fragments
    hipMemsetAsync(ws + 24379392, 0, 2048 + 262144, stream);

    pack_w<<<384, 256, 0, stream>>>(enc_Whh, whh_p, 3 * HD, HD);
    pack_w<<<24, 256, 0, stream>>>(enc_Wih, wih_p, 3 * HD, NI);
    pack_w<<<128, 256, 0, stream>>>(f_W1, w1_p, HD, HD);
    pack_w<<<128, 256, 0, stream>>>(f_W2, w2_p, HD, HD);
    pack_w<<<128, 256, 0, stream>>>(g_W, gw_p, HD, HD);
    pack_w<<<384, 256, 0, stream>>>(dec_Whh, dwhh_p, 3 * HD, HD);
    pack_w<<<8, 256, 0, stream>>>(out_W, outw_p, NI, HD);
    pack_x<<<48, 256, 0, stream>>>(x, xhi, xlo);

    void* args[] = {
        (void*)&xhi, (void*)&xlo, (void*)&wih_p, (void*)&whh_p,
        (void*)&w1_p, (void*)&w2_p, (void*)&gw_p, (void*)&dwhh_p, (void*)&outw_p,
        (void*)&enc_bih, (void*)&enc_bhh, (void*)&f_b1, (void*)&f_b2,
        (void*)&g_b, (void*)&dec_bih, (void*)&dec_bhh, (void*)&out_b,
        (void*)&noise,
        (void*)&hE0, (void*)&hE1, (void*)&hP0, (void*)&hP1, (void*)&uP,
        (void*)&h_encF, (void*)&out, (void*)&bar
    };
    hipLaunchCooperativeKernel((void*)coop_all, dim3(256), dim3(512), args, 0, stream);
}

// Round 4
// 4524.529 us; speedup vs baseline: 1.3655x; 1.3655x over previous
//
#include <hip/hip_runtime.h>
#include <math.h>

typedef __bf16 bf16x8 __attribute__((ext_vector_type(8)));
typedef float f32x4 __attribute__((ext_vector_type(4)));
typedef unsigned long long u64;

#define HD 512
#define NB 128
#define NI 32
#define NL 96
#define NS 16
#define NF 24
#define NSTEP 23
#define PAD 520   // LDS A-tile row stride in shorts: 520*2B=1040B -> rows land on
                  // distinct bank quads (260%32=4), <=2-way conflict on b128 reads

#define MFMA16(a,b,c) __builtin_amdgcn_mfma_f32_16x16x32_bf16(a,b,c,0,0,0)

__device__ __forceinline__ unsigned short f2bf(float f) {
    union { float f; unsigned u; } v; v.f = f;
    unsigned r = v.u + 0x7fffu + ((v.u >> 16) & 1u);
    return (unsigned short)(r >> 16);
}
__device__ __forceinline__ float bf2f(unsigned short h) {
    union { unsigned u; float f; } v; v.u = ((unsigned)h) << 16;
    return v.f;
}
__device__ __forceinline__ void split_bf(float v, unsigned short& hi, unsigned short& lo) {
    unsigned short h = f2bf(v);
    hi = h;
    lo = f2bf(v - bf2f(h));
}
__device__ __forceinline__ float sigm(float x) { return 1.0f / (1.0f + __expf(-x)); }
__device__ __forceinline__ float softp(float x) {
    return fmaxf(x, 0.0f) + log1pf(__expf(-fabsf(x)));
}
__device__ __forceinline__ bf16x8 ld8(const unsigned short* p) {
    return *reinterpret_cast<const bf16x8*>(p);
}
// split-bf16 3-term product: (ahi+alo)*(bhi+blo) ~= ahi*bhi + alo*bhi + ahi*blo
__device__ __forceinline__ f32x4 mfma3(bf16x8 ahi, bf16x8 alo, const unsigned short* bp, f32x4 c) {
    bf16x8 bhi = ld8(bp);
    bf16x8 blo = ld8(bp + 8);
    c = MFMA16(ahi, bhi, c);
    c = MFMA16(alo, bhi, c);
    c = MFMA16(ahi, blo, c);
    return c;
}

// ---------- prep: pack W[N][K] fp32 -> split bf16 B-fragments ----------
__global__ void pack_w(const float* __restrict__ W, unsigned short* __restrict__ Wp,
                       int N, int K) {
    int idx = blockIdx.x * 256 + threadIdx.x;
    int total = (N / 16) * (K / 32) * 64;
    if (idx >= total) return;
    int lane = idx & 63;
    int t2 = idx >> 6;
    int KT = K / 32;
    int kt = t2 % KT, nt = t2 / KT;
    const float* src = W + (size_t)(nt * 16 + (lane & 15)) * K + kt * 32 + (lane >> 4) * 8;
    unsigned short* dst = Wp + (size_t)idx * 16;
    #pragma unroll
    for (int j = 0; j < 8; ++j) split_bf(src[j], dst[j], dst[8 + j]);
}

// ---------- prep: x[B][I][L] fp32 -> xhi/xlo [L][B][I] bf16 ----------
__global__ void pack_x(const float* __restrict__ x, unsigned short* __restrict__ xhi,
                       unsigned short* __restrict__ xlo) {
    int idx = blockIdx.x * 256 + threadIdx.x;
    if (idx >= NL * NB) return;
    int b = idx % NB, l = idx / NB;
    size_t base = (size_t)(l * NB + b) * NI;
    #pragma unroll
    for (int i = 0; i < NI; ++i)
        split_bf(x[((size_t)b * NI + i) * NL + l], xhi[base + i], xlo[base + i]);
}

// =================== fused row-local kernel ===================
// Row partitioning makes every recurrence block-local:
//   encoder: 8 blocks x 16 rows (full Whh per block), 96 steps, 0 grid syncs
//   SDE+decoder: 128 blocks x 16 rows of S*B=2048, 0 grid syncs
//   ONE producer->consumer handoff (encoder -> SDE) via 8-count flag.
// Rounds 1-3 lesson: any per-step grid exchange costs ~12us through the fabric;
// __syncthreads costs ~0.05us. This trades fabric sync for per-CU MFMA density.
__global__ __launch_bounds__(512, 2) void coop_all(
    const unsigned short* __restrict__ xhi, const unsigned short* __restrict__ xlo,
    const unsigned short* __restrict__ wih_p, const unsigned short* __restrict__ whh_p,
    const unsigned short* __restrict__ w1_p, const unsigned short* __restrict__ w2_p,
    const unsigned short* __restrict__ gw_p, const unsigned short* __restrict__ dwhh_p,
    const unsigned short* __restrict__ outw_p,
    const float* __restrict__ ebih, const float* __restrict__ ebhh,
    const float* __restrict__ fb1, const float* __restrict__ fb2,
    const float* __restrict__ gb, const float* __restrict__ dbih,
    const float* __restrict__ dbhh, const float* __restrict__ outb,
    const float* __restrict__ noise,
    u64* hEh, u64* hEl, float* out, unsigned* bar)
{
    const int bid = blockIdx.x;
    const int tid = threadIdx.x, lane = tid & 63, wv = tid >> 6;
    const int l15 = lane & 15, g4 = lane >> 4;
    const f32x4 zz = {0.f, 0.f, 0.f, 0.f};

    // A-operand tiles (16 rows x 512 k) in split-bf16, frag-readable:
    // lane reads 8 shorts at [row=l15][kt*32+g4*8]
    __shared__ __align__(16) unsigned short hAhi[16][PAD], hAlo[16][PAD];
    __shared__ __align__(16) unsigned short uAhi[16][PAD], uAlo[16][PAD];

    // =============== encoder: blocks 0..7, block g owns rows g*16..+16 ===============
    if (bid < 8) {
        const int g = bid;
        float cr[4], cz[4], binx[4], bhnn[4];
        #pragma unroll
        for (int nt = 0; nt < 4; ++nt) {
            int u = wv * 64 + nt * 16 + l15;
            cr[nt] = ebih[u] + ebhh[u];
            cz[nt] = ebih[HD + u] + ebhh[HD + u];
            binx[nt] = ebih[2 * HD + u];
            bhnn[nt] = ebhh[2 * HD + u];
        }
        float hcell[4][4];
        #pragma unroll
        for (int nt = 0; nt < 4; ++nt)
            #pragma unroll
            for (int v = 0; v < 4; ++v) hcell[nt][v] = 0.f;
        for (int i = tid; i < 16 * PAD; i += 512) {
            hAhi[0][i] = 0; hAlo[0][i] = 0;
        }
        __syncthreads();

        #pragma unroll 1
        for (int l = 0; l < NL; ++l) {
            size_t xb = ((size_t)l * NB + g * 16 + l15) * NI + g4 * 8;
            bf16x8 axh = ld8(xhi + xb), axl = ld8(xlo + xb);
            f32x4 accr[4], accz[4], accin[4], acchn[4];
            #pragma unroll
            for (int nt = 0; nt < 4; ++nt) { accr[nt] = zz; accz[nt] = zz; accin[nt] = zz; acchn[nt] = zz; }
            #pragma unroll
            for (int nt = 0; nt < 4; ++nt) {
                int un = wv * 4 + nt;
                accr[nt]  = mfma3(axh, axl, wih_p + ((size_t)(un) * 64 + lane) * 16, accr[nt]);
                accz[nt]  = mfma3(axh, axl, wih_p + ((size_t)(32 + un) * 64 + lane) * 16, accz[nt]);
                accin[nt] = mfma3(axh, axl, wih_p + ((size_t)(64 + un) * 64 + lane) * 16, accin[nt]);
            }
            #pragma unroll 2
            for (int kt = 0; kt < 16; ++kt) {
                bf16x8 ah = *(const bf16x8*)&hAhi[l15][kt * 32 + g4 * 8];
                bf16x8 al = *(const bf16x8*)&hAlo[l15][kt * 32 + g4 * 8];
                #pragma unroll
                for (int nt = 0; nt < 4; ++nt) {
                    int un = wv * 4 + nt;
                    accr[nt]  = mfma3(ah, al, whh_p + ((size_t)((un) * 16 + kt) * 64 + lane) * 16, accr[nt]);
                    accz[nt]  = mfma3(ah, al, whh_p + ((size_t)((32 + un) * 16 + kt) * 64 + lane) * 16, accz[nt]);
                    acchn[nt] = mfma3(ah, al, whh_p + ((size_t)((64 + un) * 16 + kt) * 64 + lane) * 16, acchn[nt]);
                }
            }
            __syncthreads();   // all hA reads done
            #pragma unroll
            for (int nt = 0; nt < 4; ++nt)
                #pragma unroll
                for (int v = 0; v < 4; ++v) {
                    float r = sigm(accr[nt][v] + cr[nt]);
                    float z = sigm(accz[nt][v] + cz[nt]);
                    float nn = tanhf(accin[nt][v] + binx[nt] + r * (acchn[nt][v] + bhnn[nt]));
                    hcell[nt][v] = (1.f - z) * nn + z * hcell[nt][v];
                    unsigned short hi, lo;
                    split_bf(hcell[nt][v], hi, lo);
                    hAhi[g4 * 4 + v][wv * 64 + nt * 16 + l15] = hi;
                    hAlo[g4 * 4 + v][wv * 64 + nt * 16 + l15] = lo;
                }
            __syncthreads();
        }
        // publish final h (split-bf) for SDE blocks
        for (int i = tid; i < 2048; i += 512) {
            int r = i >> 7, c4 = i & 127;
            u64 qh = *(const u64*)&hAhi[r][c4 * 4];
            u64 ql = *(const u64*)&hAlo[r][c4 * 4];
            __hip_atomic_store(hEh + (size_t)(g * 16 + r) * 128 + c4, qh, __ATOMIC_RELAXED, __HIP_MEMORY_SCOPE_AGENT);
            __hip_atomic_store(hEl + (size_t)(g * 16 + r) * 128 + c4, ql, __ATOMIC_RELAXED, __HIP_MEMORY_SCOPE_AGENT);
        }
        __builtin_amdgcn_s_waitcnt(0);
        __syncthreads();
        if (tid == 0)
            __hip_atomic_fetch_add(bar, 1u, __ATOMIC_RELAXED, __HIP_MEMORY_SCOPE_AGENT);
    }

    // -------- single handoff: wait for all 8 encoder blocks --------
    if (tid == 0) {
        while (__hip_atomic_load(bar, __ATOMIC_RELAXED, __HIP_MEMORY_SCOPE_AGENT) < 8u)
            __builtin_amdgcn_s_sleep(2);
    }
    __syncthreads();

    // =============== SDE + decoder: block owns rows (s, brow..brow+16) ===============
    const int s = bid >> 3, t7 = bid & 7;
    const int brow = t7 * 16;

    // stage h_enc -> hA
    for (int i = tid; i < 2048; i += 512) {
        int r = i >> 7, c4 = i & 127;
        u64 qh = __hip_atomic_load(hEh + (size_t)(brow + r) * 128 + c4, __ATOMIC_RELAXED, __HIP_MEMORY_SCOPE_AGENT);
        u64 ql = __hip_atomic_load(hEl + (size_t)(brow + r) * 128 + c4, __ATOMIC_RELAXED, __HIP_MEMORY_SCOPE_AGENT);
        *(u64*)&hAhi[r][c4 * 4] = qh;
        *(u64*)&hAlo[r][c4 * 4] = ql;
    }
    __syncthreads();

    float hreg[4][4];
    #pragma unroll
    for (int nt = 0; nt < 4; ++nt)
        #pragma unroll
        for (int v = 0; v < 4; ++v) {
            int u = wv * 64 + nt * 16 + l15;
            hreg[nt][v] = bf2f(hAhi[g4 * 4 + v][u]) + bf2f(hAlo[g4 * 4 + v][u]);
        }

    float b1v[4], b2v[4], gbv[4];
    #pragma unroll
    for (int nt = 0; nt < 4; ++nt) {
        int u = wv * 64 + nt * 16 + l15;
        b1v[nt] = fb1[u]; b2v[nt] = fb2[u]; gbv[nt] = gb[u];
    }
    const float dt = (float)NF / (float)NSTEP;
    const float sqdt = sqrtf(dt);

    #pragma unroll 1
    for (int st = 0; st < NSTEP; ++st) {
        // ---- phase A: au = h W1^T, ag = h gW^T (per-wave 64-unit slice) ----
        f32x4 au[4], ag[4];
        #pragma unroll
        for (int nt = 0; nt < 4; ++nt) { au[nt] = zz; ag[nt] = zz; }
        #pragma unroll 2
        for (int kt = 0; kt < 16; ++kt) {
            bf16x8 ah = *(const bf16x8*)&hAhi[l15][kt * 32 + g4 * 8];
            bf16x8 al = *(const bf16x8*)&hAlo[l15][kt * 32 + g4 * 8];
            #pragma unroll
            for (int nt = 0; nt < 4; ++nt) {
                int un = wv * 4 + nt;
                au[nt] = mfma3(ah, al, w1_p + ((size_t)(un * 16 + kt) * 64 + lane) * 16, au[nt]);
                ag[nt] = mfma3(ah, al, gw_p + ((size_t)(un * 16 + kt) * 64 + lane) * 16, ag[nt]);
            }
        }
        float nz[4][4];
        #pragma unroll
        for (int nt = 0; nt < 4; ++nt)
            #pragma unroll
            for (int v = 0; v < 4; ++v)
                nz[nt][v] = noise[((size_t)(s * NSTEP + st) * NB + brow + g4 * 4 + v) * HD
                                  + wv * 64 + nt * 16 + l15];
        #pragma unroll
        for (int nt = 0; nt < 4; ++nt)
            #pragma unroll
            for (int v = 0; v < 4; ++v) {
                unsigned short hi, lo;
                split_bf(tanhf(au[nt][v] + b1v[nt]), hi, lo);
                uAhi[g4 * 4 + v][wv * 64 + nt * 16 + l15] = hi;
                uAlo[g4 * 4 + v][wv * 64 + nt * 16 + l15] = lo;
            }
        __syncthreads();   // hA reads + prev uA reads done; uA now valid
        // ---- phase B: af = u W2^T ----
        f32x4 af[4];
        #pragma unroll
        for (int nt = 0; nt < 4; ++nt) af[nt] = zz;
        #pragma unroll 2
        for (int kt = 0; kt < 16; ++kt) {
            bf16x8 uh = *(const bf16x8*)&uAhi[l15][kt * 32 + g4 * 8];
            bf16x8 ul = *(const bf16x8*)&uAlo[l15][kt * 32 + g4 * 8];
            #pragma unroll
            for (int nt = 0; nt < 4; ++nt)
                af[nt] = mfma3(uh, ul, w2_p + ((size_t)((wv * 4 + nt) * 16 + kt) * 64 + lane) * 16, af[nt]);
        }
        #pragma unroll
        for (int nt = 0; nt < 4; ++nt)
            #pragma unroll
            for (int v = 0; v < 4; ++v) {
                float gg = softp(ag[nt][v] + gbv[nt]);
                hreg[nt][v] += (af[nt][v] + b2v[nt]) * dt + gg * sqdt * nz[nt][v];
                unsigned short hi, lo;
                split_bf(hreg[nt][v], hi, lo);
                hAhi[g4 * 4 + v][wv * 64 + nt * 16 + l15] = hi;
                hAlo[g4 * 4 + v][wv * 64 + nt * 16 + l15] = lo;
            }
        __syncthreads();   // hA updated for next step
    }

    // =============== decoder GRU + out-proj (all block-local) ===============
    float crv[4], czv[4], binv[4], bhnv[4];
    #pragma unroll
    for (int nt = 0; nt < 4; ++nt) {
        int u = wv * 64 + nt * 16 + l15;
        crv[nt] = dbih[u] + dbhh[u];
        czv[nt] = dbih[HD + u] + dbhh[HD + u];
        binv[nt] = dbih[2 * HD + u];
        bhnv[nt] = dbhh[2 * HD + u];
    }
    const float obias = (wv < 2) ? outb[wv * 16 + l15] : 0.f;

    #pragma unroll 1
    for (int j = 0; j <= NF; ++j) {
        // out_{j-1} = proj(h_j): hA holds h_j at entry; waves 0-1 compute it
        if (j >= 1 && wv < 2) {
            f32x4 ao = zz;
            #pragma unroll 2
            for (int kt = 0; kt < 16; ++kt) {
                bf16x8 ah = *(const bf16x8*)&hAhi[l15][kt * 32 + g4 * 8];
                bf16x8 al = *(const bf16x8*)&hAlo[l15][kt * 32 + g4 * 8];
                ao = mfma3(ah, al, outw_p + ((size_t)(wv * 16 + kt) * 64 + lane) * 16, ao);
            }
            #pragma unroll
            for (int v = 0; v < 4; ++v)
                out[(((size_t)s * NB + brow + g4 * 4 + v) * NI + wv * 16 + l15) * NF + (j - 1)]
                    = ao[v] + obias;
        }
        if (j == NF) break;
        f32x4 ar[4], az[4], anh[4];
        #pragma unroll
        for (int nt = 0; nt < 4; ++nt) { ar[nt] = zz; az[nt] = zz; anh[nt] = zz; }
        #pragma unroll 2
        for (int kt = 0; kt < 16; ++kt) {
            bf16x8 ah = *(const bf16x8*)&hAhi[l15][kt * 32 + g4 * 8];
            bf16x8 al = *(const bf16x8*)&hAlo[l15][kt * 32 + g4 * 8];
            #pragma unroll
            for (int nt = 0; nt < 4; ++nt) {
                int un = wv * 4 + nt;
                ar[nt]  = mfma3(ah, al, dwhh_p + ((size_t)((un) * 16 + kt) * 64 + lane) * 16, ar[nt]);
                az[nt]  = mfma3(ah, al, dwhh_p + ((size_t)((32 + un) * 16 + kt) * 64 + lane) * 16, az[nt]);
                anh[nt] = mfma3(ah, al, dwhh_p + ((size_t)((64 + un) * 16 + kt) * 64 + lane) * 16, anh[nt]);
            }
        }
        #pragma unroll
        for (int nt = 0; nt < 4; ++nt)
            #pragma unroll
            for (int v = 0; v < 4; ++v) {
                float r = sigm(ar[nt][v] + crv[nt]);
                float z = sigm(az[nt][v] + czv[nt]);
                float nn2 = tanhf(binv[nt] + r * (anh[nt][v] + bhnv[nt]));
                hreg[nt][v] = (1.f - z) * nn2 + z * hreg[nt][v];
            }
        __syncthreads();   // all hA reads (gates + proj) done
        #pragma unroll
        for (int nt = 0; nt < 4; ++nt)
            #pragma unroll
            for (int v = 0; v < 4; ++v) {
                unsigned short hi, lo;
                split_bf(hreg[nt][v], hi, lo);
                hAhi[g4 * 4 + v][wv * 64 + nt * 16 + l15] = hi;
                hAlo[g4 * 4 + v][wv * 64 + nt * 16 + l15] = lo;
            }
        __syncthreads();
    }
}

extern "C" void kernel_launch(void* const* d_in, const int* in_sizes, int n_in,
                              void* d_out, int out_size, void* d_ws, size_t ws_size,
                              hipStream_t stream) {
    const float* x       = (const float*)d_in[0];
    const float* noise   = (const float*)d_in[1];
    const float* enc_Wih = (const float*)d_in[2];
    const float* enc_Whh = (const float*)d_in[3];
    const float* enc_bih = (const float*)d_in[4];
    const float* enc_bhh = (const float*)d_in[5];
    const float* f_W1    = (const float*)d_in[6];
    const float* f_b1    = (const float*)d_in[7];
    const float* f_W2    = (const float*)d_in[8];
    const float* f_b2    = (const float*)d_in[9];
    const float* g_W     = (const float*)d_in[10];
    const float* g_b     = (const float*)d_in[11];
    const float* dec_Whh = (const float*)d_in[13];
    const float* dec_bih = (const float*)d_in[14];
    const float* dec_bhh = (const float*)d_in[15];
    const float* out_W   = (const float*)d_in[16];
    const float* out_b   = (const float*)d_in[17];
    float* out = (float*)d_out;

    char* ws = (char*)d_ws;
    unsigned short* whh_p  = (unsigned short*)(ws + 0);          // 3 MB
    unsigned short* wih_p  = (unsigned short*)(ws + 3145728);    // 192 KB
    unsigned short* w1_p   = (unsigned short*)(ws + 3342336);    // 1 MB
    unsigned short* w2_p   = (unsigned short*)(ws + 4390912);    // 1 MB
    unsigned short* gw_p   = (unsigned short*)(ws + 5439488);    // 1 MB
    unsigned short* dwhh_p = (unsigned short*)(ws + 6488064);    // 3 MB
    unsigned short* outw_p = (unsigned short*)(ws + 9633792);    // 64 KB
    unsigned short* xhi    = (unsigned short*)(ws + 9699328);    // 768 KB
    unsigned short* xlo    = (unsigned short*)(ws + 10485760);   // 768 KB
    u64*            hEh    = (u64*)(ws + 11272192);              // 128 KB
    u64*            hEl    = (u64*)(ws + 11403264);              // 128 KB
    unsigned*       bar    = (unsigned*)(ws + 11534336);         // 2 KB

    hipMemsetAsync(ws + 11534336, 0, 2048, stream);

    pack_w<<<384, 256, 0, stream>>>(enc_Whh, whh_p, 3 * HD, HD);
    pack_w<<<24, 256, 0, stream>>>(enc_Wih, wih_p, 3 * HD, NI);
    pack_w<<<128, 256, 0, stream>>>(f_W1, w1_p, HD, HD);
    pack_w<<<128, 256, 0, stream>>>(f_W2, w2_p, HD, HD);
    pack_w<<<128, 256, 0, stream>>>(g_W, gw_p, HD, HD);
    pack_w<<<384, 256, 0, stream>>>(dec_Whh, dwhh_p, 3 * HD, HD);
    pack_w<<<8, 256, 0, stream>>>(out_W, outw_p, NI, HD);
    pack_x<<<48, 256, 0, stream>>>(x, xhi, xlo);

    void* args[] = {
        (void*)&xhi, (void*)&xlo, (void*)&wih_p, (void*)&whh_p,
        (void*)&w1_p, (void*)&w2_p, (void*)&gw_p, (void*)&dwhh_p, (void*)&outw_p,
        (void*)&enc_bih, (void*)&enc_bhh, (void*)&f_b1, (void*)&f_b2,
        (void*)&g_b, (void*)&dec_bih, (void*)&dec_bhh, (void*)&out_b,
        (void*)&noise,
        (void*)&hEh, (void*)&hEl, (void*)&out, (void*)&bar
    };
    hipLaunchCooperativeKernel((void*)coop_all, dim3(128), dim3(512), args, 0, stream);
}

// Round 5
// 1982.022 us; speedup vs baseline: 3.1172x; 2.2828x over previous
//
#include <hip/hip_runtime.h>
#include <math.h>

typedef __bf16 bf16x8 __attribute__((ext_vector_type(8)));
typedef float f32x4 __attribute__((ext_vector_type(4)));
typedef unsigned long long u64;

#define HD 512
#define NB 128
#define NI 32
#define NL 96
#define NS 16
#define NF 24
#define NSTEP 23
#define PAD 520   // LDS A-tile row stride in shorts

#define MFMA16(a,b,c) __builtin_amdgcn_mfma_f32_16x16x32_bf16(a,b,c,0,0,0)

__device__ __forceinline__ unsigned short f2bf(float f) {
    union { float f; unsigned u; } v; v.f = f;
    unsigned r = v.u + 0x7fffu + ((v.u >> 16) & 1u);
    return (unsigned short)(r >> 16);
}
__device__ __forceinline__ float bf2f(unsigned short h) {
    union { unsigned u; float f; } v; v.u = ((unsigned)h) << 16;
    return v.f;
}
__device__ __forceinline__ void split_bf(float v, unsigned short& hi, unsigned short& lo) {
    unsigned short h = f2bf(v);
    hi = h;
    lo = f2bf(v - bf2f(h));
}
__device__ __forceinline__ float sigm(float x) { return 1.0f / (1.0f + __expf(-x)); }
__device__ __forceinline__ float softp(float x) {
    return fmaxf(x, 0.0f) + log1pf(__expf(-fabsf(x)));
}
__device__ __forceinline__ bf16x8 ld8(const unsigned short* p) {
    return *reinterpret_cast<const bf16x8*>(p);
}
// split-bf16 3-term product: (ahi+alo)*(bhi+blo) ~= ahi*bhi + alo*bhi + ahi*blo
__device__ __forceinline__ f32x4 mfma3(bf16x8 ahi, bf16x8 alo, const unsigned short* bp, f32x4 c) {
    bf16x8 bhi = ld8(bp);
    bf16x8 blo = ld8(bp + 8);
    c = MFMA16(ahi, bhi, c);
    c = MFMA16(alo, bhi, c);
    c = MFMA16(ahi, blo, c);
    return c;
}

// ---------- prep: pack W[N][K] fp32 -> split bf16 B-fragments ----------
__global__ void pack_w(const float* __restrict__ W, unsigned short* __restrict__ Wp,
                       int N, int K) {
    int idx = blockIdx.x * 256 + threadIdx.x;
    int total = (N / 16) * (K / 32) * 64;
    if (idx >= total) return;
    int lane = idx & 63;
    int t2 = idx >> 6;
    int KT = K / 32;
    int kt = t2 % KT, nt = t2 / KT;
    const float* src = W + (size_t)(nt * 16 + (lane & 15)) * K + kt * 32 + (lane >> 4) * 8;
    unsigned short* dst = Wp + (size_t)idx * 16;
    #pragma unroll
    for (int j = 0; j < 8; ++j) split_bf(src[j], dst[j], dst[8 + j]);
}

// ---------- prep: x[B][I][L] fp32 -> xhi/xlo [L][B][I] bf16 ----------
__global__ void pack_x(const float* __restrict__ x, unsigned short* __restrict__ xhi,
                       unsigned short* __restrict__ xlo) {
    int idx = blockIdx.x * 256 + threadIdx.x;
    if (idx >= NL * NB) return;
    int b = idx % NB, l = idx / NB;
    size_t base = (size_t)(l * NB + b) * NI;
    #pragma unroll
    for (int i = 0; i < NI; ++i)
        split_bf(x[((size_t)b * NI + i) * NL + l], xhi[base + i], xlo[base + i]);
}

// =================== fused kernel ===================
// Encoder: 256 blocks = 8 m-groups x 32 n-slices. Per block per step: weight
// slice 96 KB from L2 (vs 3 MB row-local, round-4's bottleneck), 32 KB bulk
// sc1 state read (8 u64/thread, one latency exposure), flag-array barrier
// (producers store own word; ONE wave polls -- round-1's flood was 8 waves).
// SDE+decoder: round-4 row-local code verbatim (proven), 128 blocks.
__global__ __launch_bounds__(512, 2) void coop_all(
    const unsigned short* __restrict__ xhi, const unsigned short* __restrict__ xlo,
    const unsigned short* __restrict__ wih_p, const unsigned short* __restrict__ whh_p,
    const unsigned short* __restrict__ w1_p, const unsigned short* __restrict__ w2_p,
    const unsigned short* __restrict__ gw_p, const unsigned short* __restrict__ dwhh_p,
    const unsigned short* __restrict__ outw_p,
    const float* __restrict__ ebih, const float* __restrict__ ebhh,
    const float* __restrict__ fb1, const float* __restrict__ fb2,
    const float* __restrict__ gb, const float* __restrict__ dbih,
    const float* __restrict__ dbhh, const float* __restrict__ outb,
    const float* __restrict__ noise,
    u64* hS0h, u64* hS0l, u64* hS1h, u64* hS1l,
    float* out, unsigned* bar)
{
    const int bid = blockIdx.x;
    const int tid = threadIdx.x, lane = tid & 63, wv = tid >> 6;
    const int l15 = lane & 15, g4 = lane >> 4;
    const f32x4 zz = {0.f, 0.f, 0.f, 0.f};

    __shared__ float pred[4][8][16][16];                       // 32 KB
    __shared__ __align__(16) unsigned short hAhi[16][PAD];     // A-tile hi
    __shared__ __align__(16) unsigned short hAlo[16][PAD];     // A-tile lo
    __shared__ __align__(16) unsigned short uAhi[16][PAD];     // SDE phase-B
    __shared__ __align__(16) unsigned short uAlo[16][PAD];
    __shared__ __align__(16) unsigned short Shi[16][16], Slo[16][16];  // h-slice stage

    u64* bufh[2] = {hS0h, hS1h};
    u64* bufl[2] = {hS0l, hS1l};

    // =============== encoder: m = bid>>5 (16 rows), n = bid&31 (16 units) ===============
    {
        const int m = bid >> 5, n = bid & 31;
        unsigned* fl = bar + m * 32;   // group's 32 flag words (128 B line)
        float cr = 0.f, cz = 0.f, binx = 0.f, bhnn = 0.f, hcell = 0.f;
        const int crow = tid >> 4, cunit = tid & 15;
        if (tid < 256) {
            int u = n * 16 + cunit;
            cr = ebih[u] + ebhh[u];
            cz = ebih[HD + u] + ebhh[HD + u];
            binx = ebih[2 * HD + u];
            bhnn = ebhh[2 * HD + u];
        }
        #pragma unroll 1
        for (int l = 0; l < NL; ++l) {
            // x loads are flag-independent: issue before the wait (wave 0 only)
            bf16x8 axh, axl;
            if (wv == 0) {
                size_t xb = ((size_t)l * NB + m * 16 + l15) * NI + g4 * 8;
                axh = ld8(xhi + xb);
                axl = ld8(xlo + xb);
            }
            // wait: h(l) complete (all 32 producers of this m-group at seq >= l)
            if (l > 0) {
                if (wv == 0) {
                    for (;;) {
                        unsigned v = __hip_atomic_load(fl + (lane & 31),
                                     __ATOMIC_RELAXED, __HIP_MEMORY_SCOPE_AGENT);
                        if (__all((int)(v >= (unsigned)l))) break;
                        __builtin_amdgcn_s_sleep(2);
                    }
                }
                __syncthreads();
            }
            // bulk read rows m*16..+16 of buf[l&1] -> LDS (loads first, then LDS writes)
            {
                const u64* sh = bufh[l & 1];
                const u64* sl = bufl[l & 1];
                u64 qh[4], ql[4];
                #pragma unroll
                for (int rep = 0; rep < 4; ++rep) {
                    int idx = rep * 512 + tid;            // 0..2047
                    int r = idx >> 7, c4 = idx & 127;
                    qh[rep] = __hip_atomic_load(sh + (size_t)(m * 16 + r) * 128 + c4,
                                                __ATOMIC_RELAXED, __HIP_MEMORY_SCOPE_AGENT);
                    ql[rep] = __hip_atomic_load(sl + (size_t)(m * 16 + r) * 128 + c4,
                                                __ATOMIC_RELAXED, __HIP_MEMORY_SCOPE_AGENT);
                }
                #pragma unroll
                for (int rep = 0; rep < 4; ++rep) {
                    int idx = rep * 512 + tid;
                    int r = idx >> 7, c4 = idx & 127;
                    *(u64*)&hAhi[r][c4 * 4] = qh[rep];
                    *(u64*)&hAlo[r][c4 * 4] = ql[rep];
                }
            }
            __syncthreads();
            // MFMA: wave wv covers kt = wv*2..+2 for the 3 gate n-tiles
            f32x4 pr = zz, pz = zz, pnh = zz, pnx = zz;
            if (wv == 0) {
                pr  = mfma3(axh, axl, wih_p + ((size_t)(0 * 32 + n) * 64 + lane) * 16, pr);
                pz  = mfma3(axh, axl, wih_p + ((size_t)(1 * 32 + n) * 64 + lane) * 16, pz);
                pnx = mfma3(axh, axl, wih_p + ((size_t)(2 * 32 + n) * 64 + lane) * 16, pnx);
            }
            #pragma unroll
            for (int kk = 0; kk < 2; ++kk) {
                int kt = wv * 2 + kk;
                bf16x8 ah = *(const bf16x8*)&hAhi[l15][kt * 32 + g4 * 8];
                bf16x8 al = *(const bf16x8*)&hAlo[l15][kt * 32 + g4 * 8];
                pr  = mfma3(ah, al, whh_p + ((size_t)((0 * 32 + n) * 16 + kt) * 64 + lane) * 16, pr);
                pz  = mfma3(ah, al, whh_p + ((size_t)((1 * 32 + n) * 16 + kt) * 64 + lane) * 16, pz);
                pnh = mfma3(ah, al, whh_p + ((size_t)((2 * 32 + n) * 16 + kt) * 64 + lane) * 16, pnh);
            }
            #pragma unroll
            for (int v = 0; v < 4; ++v) {
                pred[0][wv][g4 * 4 + v][l15] = pr[v];
                pred[1][wv][g4 * 4 + v][l15] = pz[v];
                pred[2][wv][g4 * 4 + v][l15] = pnh[v];
                if (wv == 0) pred[3][0][g4 * 4 + v][l15] = pnx[v];
            }
            __syncthreads();
            if (tid < 256) {
                float ar = 0.f, az = 0.f, anh_ = 0.f;
                #pragma unroll
                for (int w = 0; w < 8; ++w) {
                    ar += pred[0][w][crow][cunit];
                    az += pred[1][w][crow][cunit];
                    anh_ += pred[2][w][crow][cunit];
                }
                float anx_ = pred[3][0][crow][cunit];
                float r = sigm(ar + cr);
                float z = sigm(az + cz);
                float nn = tanhf(anx_ + binx + r * (anh_ + bhnn));
                hcell = (1.f - z) * nn + z * hcell;
                unsigned short hi, lo;
                split_bf(hcell, hi, lo);
                Shi[crow][cunit] = hi;
                Slo[crow][cunit] = lo;
            }
            __syncthreads();
            // publish slice: rows m*16..+16, cols n*16..+16 into buf[(l+1)&1]
            if (tid < 128) {
                int p = tid >> 6, t = tid & 63;
                int r = t >> 2, c4 = t & 3;
                u64 q = p ? *(const u64*)&Slo[r][c4 * 4] : *(const u64*)&Shi[r][c4 * 4];
                u64* dst = p ? bufl[(l + 1) & 1] : bufh[(l + 1) & 1];
                __hip_atomic_store(dst + (size_t)(m * 16 + r) * 128 + n * 4 + c4, q,
                                   __ATOMIC_RELAXED, __HIP_MEMORY_SCOPE_AGENT);
            }
            __builtin_amdgcn_s_waitcnt(0);
            __syncthreads();
            if (tid == 0)
                __hip_atomic_store(fl + n, (unsigned)(l + 1),
                                   __ATOMIC_RELAXED, __HIP_MEMORY_SCOPE_AGENT);
        }
        // encoder-done counter (final h lives in hS0: l=95 writes buf[(95+1)&1]=0)
        if (tid == 0)
            __hip_atomic_fetch_add(bar + 256, 1u, __ATOMIC_RELAXED, __HIP_MEMORY_SCOPE_AGENT);
    }

    if (bid >= 128) return;

    // -------- single handoff: wait for all 256 encoder blocks --------
    if (tid == 0) {
        while (__hip_atomic_load(bar + 256, __ATOMIC_RELAXED, __HIP_MEMORY_SCOPE_AGENT) < 256u)
            __builtin_amdgcn_s_sleep(2);
    }
    __syncthreads();

    // =============== SDE + decoder: block owns rows (s, brow..brow+16) ===============
    const int s = bid >> 3, t7 = bid & 7;
    const int brow = t7 * 16;

    // stage h_enc -> hA
    for (int i = tid; i < 2048; i += 512) {
        int r = i >> 7, c4 = i & 127;
        u64 qh = __hip_atomic_load(hS0h + (size_t)(brow + r) * 128 + c4, __ATOMIC_RELAXED, __HIP_MEMORY_SCOPE_AGENT);
        u64 ql = __hip_atomic_load(hS0l + (size_t)(brow + r) * 128 + c4, __ATOMIC_RELAXED, __HIP_MEMORY_SCOPE_AGENT);
        *(u64*)&hAhi[r][c4 * 4] = qh;
        *(u64*)&hAlo[r][c4 * 4] = ql;
    }
    __syncthreads();

    float hreg[4][4];
    #pragma unroll
    for (int nt = 0; nt < 4; ++nt)
        #pragma unroll
        for (int v = 0; v < 4; ++v) {
            int u = wv * 64 + nt * 16 + l15;
            hreg[nt][v] = bf2f(hAhi[g4 * 4 + v][u]) + bf2f(hAlo[g4 * 4 + v][u]);
        }

    float b1v[4], b2v[4], gbv[4];
    #pragma unroll
    for (int nt = 0; nt < 4; ++nt) {
        int u = wv * 64 + nt * 16 + l15;
        b1v[nt] = fb1[u]; b2v[nt] = fb2[u]; gbv[nt] = gb[u];
    }
    const float dt = (float)NF / (float)NSTEP;
    const float sqdt = sqrtf(dt);

    #pragma unroll 1
    for (int st = 0; st < NSTEP; ++st) {
        // ---- phase A: au = h W1^T, ag = h gW^T (per-wave 64-unit slice) ----
        f32x4 au[4], ag[4];
        #pragma unroll
        for (int nt = 0; nt < 4; ++nt) { au[nt] = zz; ag[nt] = zz; }
        #pragma unroll 2
        for (int kt = 0; kt < 16; ++kt) {
            bf16x8 ah = *(const bf16x8*)&hAhi[l15][kt * 32 + g4 * 8];
            bf16x8 al = *(const bf16x8*)&hAlo[l15][kt * 32 + g4 * 8];
            #pragma unroll
            for (int nt = 0; nt < 4; ++nt) {
                int un = wv * 4 + nt;
                au[nt] = mfma3(ah, al, w1_p + ((size_t)(un * 16 + kt) * 64 + lane) * 16, au[nt]);
                ag[nt] = mfma3(ah, al, gw_p + ((size_t)(un * 16 + kt) * 64 + lane) * 16, ag[nt]);
            }
        }
        float nz[4][4];
        #pragma unroll
        for (int nt = 0; nt < 4; ++nt)
            #pragma unroll
            for (int v = 0; v < 4; ++v)
                nz[nt][v] = noise[((size_t)(s * NSTEP + st) * NB + brow + g4 * 4 + v) * HD
                                  + wv * 64 + nt * 16 + l15];
        #pragma unroll
        for (int nt = 0; nt < 4; ++nt)
            #pragma unroll
            for (int v = 0; v < 4; ++v) {
                unsigned short hi, lo;
                split_bf(tanhf(au[nt][v] + b1v[nt]), hi, lo);
                uAhi[g4 * 4 + v][wv * 64 + nt * 16 + l15] = hi;
                uAlo[g4 * 4 + v][wv * 64 + nt * 16 + l15] = lo;
            }
        __syncthreads();   // hA reads + prev uA reads done; uA now valid
        // ---- phase B: af = u W2^T ----
        f32x4 af[4];
        #pragma unroll
        for (int nt = 0; nt < 4; ++nt) af[nt] = zz;
        #pragma unroll 2
        for (int kt = 0; kt < 16; ++kt) {
            bf16x8 uh = *(const bf16x8*)&uAhi[l15][kt * 32 + g4 * 8];
            bf16x8 ul = *(const bf16x8*)&uAlo[l15][kt * 32 + g4 * 8];
            #pragma unroll
            for (int nt = 0; nt < 4; ++nt)
                af[nt] = mfma3(uh, ul, w2_p + ((size_t)((wv * 4 + nt) * 16 + kt) * 64 + lane) * 16, af[nt]);
        }
        #pragma unroll
        for (int nt = 0; nt < 4; ++nt)
            #pragma unroll
            for (int v = 0; v < 4; ++v) {
                float gg = softp(ag[nt][v] + gbv[nt]);
                hreg[nt][v] += (af[nt][v] + b2v[nt]) * dt + gg * sqdt * nz[nt][v];
                unsigned short hi, lo;
                split_bf(hreg[nt][v], hi, lo);
                hAhi[g4 * 4 + v][wv * 64 + nt * 16 + l15] = hi;
                hAlo[g4 * 4 + v][wv * 64 + nt * 16 + l15] = lo;
            }
        __syncthreads();   // hA updated for next step
    }

    // =============== decoder GRU + out-proj (all block-local) ===============
    float crv[4], czv[4], binv[4], bhnv[4];
    #pragma unroll
    for (int nt = 0; nt < 4; ++nt) {
        int u = wv * 64 + nt * 16 + l15;
        crv[nt] = dbih[u] + dbhh[u];
        czv[nt] = dbih[HD + u] + dbhh[HD + u];
        binv[nt] = dbih[2 * HD + u];
        bhnv[nt] = dbhh[2 * HD + u];
    }
    const float obias = (wv < 2) ? outb[wv * 16 + l15] : 0.f;

    #pragma unroll 1
    for (int j = 0; j <= NF; ++j) {
        // out_{j-1} = proj(h_j): hA holds h_j at entry; waves 0-1 compute it
        if (j >= 1 && wv < 2) {
            f32x4 ao = zz;
            #pragma unroll 2
            for (int kt = 0; kt < 16; ++kt) {
                bf16x8 ah = *(const bf16x8*)&hAhi[l15][kt * 32 + g4 * 8];
                bf16x8 al = *(const bf16x8*)&hAlo[l15][kt * 32 + g4 * 8];
                ao = mfma3(ah, al, outw_p + ((size_t)(wv * 16 + kt) * 64 + lane) * 16, ao);
            }
            #pragma unroll
            for (int v = 0; v < 4; ++v)
                out[(((size_t)s * NB + brow + g4 * 4 + v) * NI + wv * 16 + l15) * NF + (j - 1)]
                    = ao[v] + obias;
        }
        if (j == NF) break;
        f32x4 ar[4], az[4], anh[4];
        #pragma unroll
        for (int nt = 0; nt < 4; ++nt) { ar[nt] = zz; az[nt] = zz; anh[nt] = zz; }
        #pragma unroll 2
        for (int kt = 0; kt < 16; ++kt) {
            bf16x8 ah = *(const bf16x8*)&hAhi[l15][kt * 32 + g4 * 8];
            bf16x8 al = *(const bf16x8*)&hAlo[l15][kt * 32 + g4 * 8];
            #pragma unroll
            for (int nt = 0; nt < 4; ++nt) {
                int un = wv * 4 + nt;
                ar[nt]  = mfma3(ah, al, dwhh_p + ((size_t)((un) * 16 + kt) * 64 + lane) * 16, ar[nt]);
                az[nt]  = mfma3(ah, al, dwhh_p + ((size_t)((32 + un) * 16 + kt) * 64 + lane) * 16, az[nt]);
                anh[nt] = mfma3(ah, al, dwhh_p + ((size_t)((64 + un) * 16 + kt) * 64 + lane) * 16, anh[nt]);
            }
        }
        #pragma unroll
        for (int nt = 0; nt < 4; ++nt)
            #pragma unroll
            for (int v = 0; v < 4; ++v) {
                float r = sigm(ar[nt][v] + crv[nt]);
                float z = sigm(az[nt][v] + czv[nt]);
                float nn2 = tanhf(binv[nt] + r * (anh[nt][v] + bhnv[nt]));
                hreg[nt][v] = (1.f - z) * nn2 + z * hreg[nt][v];
            }
        __syncthreads();   // all hA reads (gates + proj) done
        #pragma unroll
        for (int nt = 0; nt < 4; ++nt)
            #pragma unroll
            for (int v = 0; v < 4; ++v) {
                unsigned short hi, lo;
                split_bf(hreg[nt][v], hi, lo);
                hAhi[g4 * 4 + v][wv * 64 + nt * 16 + l15] = hi;
                hAlo[g4 * 4 + v][wv * 64 + nt * 16 + l15] = lo;
            }
        __syncthreads();
    }
}

extern "C" void kernel_launch(void* const* d_in, const int* in_sizes, int n_in,
                              void* d_out, int out_size, void* d_ws, size_t ws_size,
                              hipStream_t stream) {
    const float* x       = (const float*)d_in[0];
    const float* noise   = (const float*)d_in[1];
    const float* enc_Wih = (const float*)d_in[2];
    const float* enc_Whh = (const float*)d_in[3];
    const float* enc_bih = (const float*)d_in[4];
    const float* enc_bhh = (const float*)d_in[5];
    const float* f_W1    = (const float*)d_in[6];
    const float* f_b1    = (const float*)d_in[7];
    const float* f_W2    = (const float*)d_in[8];
    const float* f_b2    = (const float*)d_in[9];
    const float* g_W     = (const float*)d_in[10];
    const float* g_b     = (const float*)d_in[11];
    const float* dec_Whh = (const float*)d_in[13];
    const float* dec_bih = (const float*)d_in[14];
    const float* dec_bhh = (const float*)d_in[15];
    const float* out_W   = (const float*)d_in[16];
    const float* out_b   = (const float*)d_in[17];
    float* out = (float*)d_out;

    char* ws = (char*)d_ws;
    unsigned short* whh_p  = (unsigned short*)(ws + 0);          // 3 MB
    unsigned short* wih_p  = (unsigned short*)(ws + 3145728);    // 192 KB
    unsigned short* w1_p   = (unsigned short*)(ws + 3342336);    // 1 MB
    unsigned short* w2_p   = (unsigned short*)(ws + 4390912);    // 1 MB
    unsigned short* gw_p   = (unsigned short*)(ws + 5439488);    // 1 MB
    unsigned short* dwhh_p = (unsigned short*)(ws + 6488064);    // 3 MB
    unsigned short* outw_p = (unsigned short*)(ws + 9633792);    // 64 KB
    unsigned short* xhi    = (unsigned short*)(ws + 9699328);    // 768 KB
    unsigned short* xlo    = (unsigned short*)(ws + 10485760);   // 768 KB
    u64*            hS0h   = (u64*)(ws + 11272192);              // 128 KB [128][128]
    u64*            hS0l   = (u64*)(ws + 11403264);              // 128 KB
    u64*            hS1h   = (u64*)(ws + 11534336);              // 128 KB
    u64*            hS1l   = (u64*)(ws + 11665408);              // 128 KB
    unsigned*       bar    = (unsigned*)(ws + 11796480);         // 2 KB: flags[8][32] + ctr

    // zero h(0) state buffer + flags/counter
    hipMemsetAsync(ws + 11272192, 0, 262144, stream);
    hipMemsetAsync(ws + 11796480, 0, 2048, stream);

    pack_w<<<384, 256, 0, stream>>>(enc_Whh, whh_p, 3 * HD, HD);
    pack_w<<<24, 256, 0, stream>>>(enc_Wih, wih_p, 3 * HD, NI);
    pack_w<<<128, 256, 0, stream>>>(f_W1, w1_p, HD, HD);
    pack_w<<<128, 256, 0, stream>>>(f_W2, w2_p, HD, HD);
    pack_w<<<128, 256, 0, stream>>>(g_W, gw_p, HD, HD);
    pack_w<<<384, 256, 0, stream>>>(dec_Whh, dwhh_p, 3 * HD, HD);
    pack_w<<<8, 256, 0, stream>>>(out_W, outw_p, NI, HD);
    pack_x<<<48, 256, 0, stream>>>(x, xhi, xlo);

    void* args[] = {
        (void*)&xhi, (void*)&xlo, (void*)&wih_p, (void*)&whh_p,
        (void*)&w1_p, (void*)&w2_p, (void*)&gw_p, (void*)&dwhh_p, (void*)&outw_p,
        (void*)&enc_bih, (void*)&enc_bhh, (void*)&f_b1, (void*)&f_b2,
        (void*)&g_b, (void*)&dec_bih, (void*)&dec_bhh, (void*)&out_b,
        (void*)&noise,
        (void*)&hS0h, (void*)&hS0l, (void*)&hS1h, (void*)&hS1l,
        (void*)&out, (void*)&bar
    };
    hipLaunchCooperativeKernel((void*)coop_all, dim3(256), dim3(512), args, 0, stream);
}

// Round 6
// 1861.975 us; speedup vs baseline: 3.3182x; 1.0645x over previous
//
#include <hip/hip_runtime.h>
#include <math.h>

typedef __bf16 bf16x8 __attribute__((ext_vector_type(8)));
typedef float f32x4 __attribute__((ext_vector_type(4)));
typedef unsigned long long u64;

#define HD 512
#define NB 128
#define NI 32
#define NL 96
#define NS 16
#define NF 24
#define NSTEP 23
#define PAD 520   // LDS A-tile row stride in shorts

#define MFMA16(a,b,c) __builtin_amdgcn_mfma_f32_16x16x32_bf16(a,b,c,0,0,0)

__device__ __forceinline__ unsigned short f2bf(float f) {
    union { float f; unsigned u; } v; v.f = f;
    unsigned r = v.u + 0x7fffu + ((v.u >> 16) & 1u);
    return (unsigned short)(r >> 16);
}
__device__ __forceinline__ float bf2f(unsigned short h) {
    union { unsigned u; float f; } v; v.u = ((unsigned)h) << 16;
    return v.f;
}
__device__ __forceinline__ void split_bf(float v, unsigned short& hi, unsigned short& lo) {
    unsigned short h = f2bf(v);
    hi = h;
    lo = f2bf(v - bf2f(h));
}
__device__ __forceinline__ float sigm(float x) { return 1.0f / (1.0f + __expf(-x)); }
__device__ __forceinline__ float softp(float x) {
    return fmaxf(x, 0.0f) + log1pf(__expf(-fabsf(x)));
}
__device__ __forceinline__ bf16x8 ld8(const unsigned short* p) {
    return *reinterpret_cast<const bf16x8*>(p);
}
// split-bf16 3-term product: (ahi+alo)*(bhi+blo) ~= ahi*bhi + alo*bhi + ahi*blo
__device__ __forceinline__ f32x4 mfma3(bf16x8 ahi, bf16x8 alo, const unsigned short* bp, f32x4 c) {
    bf16x8 bhi = ld8(bp);
    bf16x8 blo = ld8(bp + 8);
    c = MFMA16(ahi, bhi, c);
    c = MFMA16(alo, bhi, c);
    c = MFMA16(ahi, blo, c);
    return c;
}

// ---- proven exchange primitives (round 5) ----
// producer: drain vmem, block barrier, tid0 publishes monotonic seq flag
__device__ __forceinline__ void sigval(unsigned* slot, unsigned val, int tid) {
    __builtin_amdgcn_s_waitcnt(0);
    __syncthreads();
    if (tid == 0)
        __hip_atomic_store(slot, val, __ATOMIC_RELAXED, __HIP_MEMORY_SCOPE_AGENT);
}
// consumer: ONE wave polls the group's 8 flags (round-1 lesson: never more)
__device__ __forceinline__ void poll8(const unsigned* f, unsigned tgt, int wv, int lane) {
    if (wv == 0) {
        for (;;) {
            unsigned v = __hip_atomic_load(f + (lane & 7), __ATOMIC_RELAXED, __HIP_MEMORY_SCOPE_AGENT);
            if (__all((int)(v >= tgt))) break;
            __builtin_amdgcn_s_sleep(2);
        }
    }
    __syncthreads();
}
// bulk stage 64 rows x 512 cols (split planes) global -> LDS A-tile (chunked loads)
__device__ __forceinline__ void stage64(const u64* sh, const u64* sl, int r0,
        unsigned short (*Ahi)[16][PAD], unsigned short (*Alo)[16][PAD], int tid) {
    #pragma unroll 1
    for (int c = 0; c < 4; ++c) {
        u64 th[4], tl[4];
        #pragma unroll
        for (int k = 0; k < 4; ++k) {
            int idx = (c * 4 + k) * 512 + tid;   // 0..8191
            int r = idx >> 7, c4 = idx & 127;
            th[k] = __hip_atomic_load(sh + (size_t)(r0 + r) * 128 + c4,
                                      __ATOMIC_RELAXED, __HIP_MEMORY_SCOPE_AGENT);
            tl[k] = __hip_atomic_load(sl + (size_t)(r0 + r) * 128 + c4,
                                      __ATOMIC_RELAXED, __HIP_MEMORY_SCOPE_AGENT);
        }
        #pragma unroll
        for (int k = 0; k < 4; ++k) {
            int idx = (c * 4 + k) * 512 + tid;
            int r = idx >> 7, c4 = idx & 127;
            *(u64*)&Ahi[r >> 4][r & 15][c4 * 4] = th[k];
            *(u64*)&Alo[r >> 4][r & 15][c4 * 4] = tl[k];
        }
    }
}
// bulk publish block's 64x64 slice LDS -> global planes
__device__ __forceinline__ void publish64(u64* dh, u64* dl, int r0, int u0c,
        unsigned short (*Bhi)[72], unsigned short (*Blo)[72], int tid) {
    #pragma unroll
    for (int rep = 0; rep < 4; ++rep) {
        int idx = rep * 512 + tid;          // 0..2047
        int pl = idx >> 10, e = idx & 1023;
        int r = e >> 4, c = e & 15;
        u64 q = pl ? *(const u64*)&Blo[r][c * 4] : *(const u64*)&Bhi[r][c * 4];
        u64* dst = (pl ? dl : dh) + (size_t)(r0 + r) * 128 + u0c + c;
        __hip_atomic_store(dst, q, __ATOMIC_RELAXED, __HIP_MEMORY_SCOPE_AGENT);
    }
}

// ---------- prep: pack W[N][K] fp32 -> split bf16 B-fragments ----------
__global__ void pack_w(const float* __restrict__ W, unsigned short* __restrict__ Wp,
                       int N, int K) {
    int idx = blockIdx.x * 256 + threadIdx.x;
    int total = (N / 16) * (K / 32) * 64;
    if (idx >= total) return;
    int lane = idx & 63;
    int t2 = idx >> 6;
    int KT = K / 32;
    int kt = t2 % KT, nt = t2 / KT;
    const float* src = W + (size_t)(nt * 16 + (lane & 15)) * K + kt * 32 + (lane >> 4) * 8;
    unsigned short* dst = Wp + (size_t)idx * 16;
    #pragma unroll
    for (int j = 0; j < 8; ++j) split_bf(src[j], dst[j], dst[8 + j]);
}

// ---------- prep: x[B][I][L] fp32 -> xhi/xlo [L][B][I] bf16 ----------
__global__ void pack_x(const float* __restrict__ x, unsigned short* __restrict__ xhi,
                       unsigned short* __restrict__ xlo) {
    int idx = blockIdx.x * 256 + threadIdx.x;
    if (idx >= NL * NB) return;
    int b = idx % NB, l = idx / NB;
    size_t base = (size_t)(l * NB + b) * NI;
    #pragma unroll
    for (int i = 0; i < NI; ++i)
        split_bf(x[((size_t)b * NI + i) * NL + l], xhi[base + i], xlo[base + i]);
}

// =================== fused kernel ===================
// Encoder (round-5, proven): 256 blocks = 8 m-groups x 32 n-slices.
// SDE+decoder (NEW): 256 blocks = 32 row-groups (64 rows of S*B=2048) x 8
// unit-slices (64 units). Weight stream/block/step: 3MB -> 384 KB (the round-4
// bottleneck). Exchanges via the proven flag+bulk-sc1 pattern; h double-buffered
// by step parity, u single-buffered (WAR-safe via full-group flag waits).
__global__ __launch_bounds__(512, 2) void coop_all(
    const unsigned short* __restrict__ xhi, const unsigned short* __restrict__ xlo,
    const unsigned short* __restrict__ wih_p, const unsigned short* __restrict__ whh_p,
    const unsigned short* __restrict__ w1_p, const unsigned short* __restrict__ w2_p,
    const unsigned short* __restrict__ gw_p, const unsigned short* __restrict__ dwhh_p,
    const unsigned short* __restrict__ outw_p,
    const float* __restrict__ ebih, const float* __restrict__ ebhh,
    const float* __restrict__ fb1, const float* __restrict__ fb2,
    const float* __restrict__ gb, const float* __restrict__ dbih,
    const float* __restrict__ dbhh, const float* __restrict__ outb,
    const float* __restrict__ noise,
    u64* hS0h, u64* hS0l, u64* hS1h, u64* hS1l,
    u64* uPh, u64* uPl, u64* hD0h, u64* hD0l, u64* hD1h, u64* hD1l,
    float* out, unsigned* bar)
{
    const int bid = blockIdx.x;
    const int tid = threadIdx.x, lane = tid & 63, wv = tid >> 6;
    const int l15 = lane & 15, g4 = lane >> 4;
    const f32x4 zz = {0.f, 0.f, 0.f, 0.f};

    // LDS overlay: encoder phase uses [pred|ehA|S] (67 KB); SDE phase uses
    // [hA64 133KB | uS 18KB] = 151552 B total footprint.
    __shared__ __align__(16) unsigned char SM[151552];
    auto hA64hi = reinterpret_cast<unsigned short (*)[16][PAD]>(SM);           // [4][16][PAD]
    auto hA64lo = reinterpret_cast<unsigned short (*)[16][PAD]>(SM + 66560);
    auto uShi   = reinterpret_cast<unsigned short (*)[72]>(SM + 133120);       // [64][72]
    auto uSlo   = reinterpret_cast<unsigned short (*)[72]>(SM + 142336);
    auto pred   = reinterpret_cast<float (*)[8][16][16]>(SM);                  // [4][8][16][16]
    auto ehAhi  = reinterpret_cast<unsigned short (*)[PAD]>(SM + 32768);       // [16][PAD]
    auto ehAlo  = reinterpret_cast<unsigned short (*)[PAD]>(SM + 49408);
    auto Shi    = reinterpret_cast<unsigned short (*)[16]>(SM + 66048);        // [16][16]
    auto Slo    = reinterpret_cast<unsigned short (*)[16]>(SM + 66560);

    u64* bufh[2] = {hS0h, hS1h};
    u64* bufl[2] = {hS0l, hS1l};

    // =============== encoder: m = bid>>5 (16 rows), n = bid&31 (16 units) ===============
    {
        const int m = bid >> 5, n = bid & 31;
        unsigned* fl = bar + m * 32;
        float cr = 0.f, cz = 0.f, binx = 0.f, bhnn = 0.f, hcell = 0.f;
        const int crow = tid >> 4, cunit = tid & 15;
        if (tid < 256) {
            int u = n * 16 + cunit;
            cr = ebih[u] + ebhh[u];
            cz = ebih[HD + u] + ebhh[HD + u];
            binx = ebih[2 * HD + u];
            bhnn = ebhh[2 * HD + u];
        }
        #pragma unroll 1
        for (int l = 0; l < NL; ++l) {
            bf16x8 axh, axl;
            if (wv == 0) {
                size_t xb = ((size_t)l * NB + m * 16 + l15) * NI + g4 * 8;
                axh = ld8(xhi + xb);
                axl = ld8(xlo + xb);
            }
            if (l > 0) {
                if (wv == 0) {
                    for (;;) {
                        unsigned v = __hip_atomic_load(fl + (lane & 31),
                                     __ATOMIC_RELAXED, __HIP_MEMORY_SCOPE_AGENT);
                        if (__all((int)(v >= (unsigned)l))) break;
                        __builtin_amdgcn_s_sleep(2);
                    }
                }
                __syncthreads();
            }
            {
                const u64* sh = bufh[l & 1];
                const u64* sl = bufl[l & 1];
                u64 qh[4], ql[4];
                #pragma unroll
                for (int rep = 0; rep < 4; ++rep) {
                    int idx = rep * 512 + tid;
                    int r = idx >> 7, c4 = idx & 127;
                    qh[rep] = __hip_atomic_load(sh + (size_t)(m * 16 + r) * 128 + c4,
                                                __ATOMIC_RELAXED, __HIP_MEMORY_SCOPE_AGENT);
                    ql[rep] = __hip_atomic_load(sl + (size_t)(m * 16 + r) * 128 + c4,
                                                __ATOMIC_RELAXED, __HIP_MEMORY_SCOPE_AGENT);
                }
                #pragma unroll
                for (int rep = 0; rep < 4; ++rep) {
                    int idx = rep * 512 + tid;
                    int r = idx >> 7, c4 = idx & 127;
                    *(u64*)&ehAhi[r][c4 * 4] = qh[rep];
                    *(u64*)&ehAlo[r][c4 * 4] = ql[rep];
                }
            }
            __syncthreads();
            f32x4 pr = zz, pz = zz, pnh = zz, pnx = zz;
            if (wv == 0) {
                pr  = mfma3(axh, axl, wih_p + ((size_t)(0 * 32 + n) * 64 + lane) * 16, pr);
                pz  = mfma3(axh, axl, wih_p + ((size_t)(1 * 32 + n) * 64 + lane) * 16, pz);
                pnx = mfma3(axh, axl, wih_p + ((size_t)(2 * 32 + n) * 64 + lane) * 16, pnx);
            }
            #pragma unroll
            for (int kk = 0; kk < 2; ++kk) {
                int kt = wv * 2 + kk;
                bf16x8 ah = *(const bf16x8*)&ehAhi[l15][kt * 32 + g4 * 8];
                bf16x8 al = *(const bf16x8*)&ehAlo[l15][kt * 32 + g4 * 8];
                pr  = mfma3(ah, al, whh_p + ((size_t)((0 * 32 + n) * 16 + kt) * 64 + lane) * 16, pr);
                pz  = mfma3(ah, al, whh_p + ((size_t)((1 * 32 + n) * 16 + kt) * 64 + lane) * 16, pz);
                pnh = mfma3(ah, al, whh_p + ((size_t)((2 * 32 + n) * 16 + kt) * 64 + lane) * 16, pnh);
            }
            #pragma unroll
            for (int v = 0; v < 4; ++v) {
                pred[0][wv][g4 * 4 + v][l15] = pr[v];
                pred[1][wv][g4 * 4 + v][l15] = pz[v];
                pred[2][wv][g4 * 4 + v][l15] = pnh[v];
                if (wv == 0) pred[3][0][g4 * 4 + v][l15] = pnx[v];
            }
            __syncthreads();
            if (tid < 256) {
                float ar = 0.f, az = 0.f, anh_ = 0.f;
                #pragma unroll
                for (int w = 0; w < 8; ++w) {
                    ar += pred[0][w][crow][cunit];
                    az += pred[1][w][crow][cunit];
                    anh_ += pred[2][w][crow][cunit];
                }
                float anx_ = pred[3][0][crow][cunit];
                float r = sigm(ar + cr);
                float z = sigm(az + cz);
                float nn = tanhf(anx_ + binx + r * (anh_ + bhnn));
                hcell = (1.f - z) * nn + z * hcell;
                unsigned short hi, lo;
                split_bf(hcell, hi, lo);
                Shi[crow][cunit] = hi;
                Slo[crow][cunit] = lo;
            }
            __syncthreads();
            if (tid < 128) {
                int p = tid >> 6, t = tid & 63;
                int r = t >> 2, c4 = t & 3;
                u64 q = p ? *(const u64*)&Slo[r][c4 * 4] : *(const u64*)&Shi[r][c4 * 4];
                u64* dst = p ? bufl[(l + 1) & 1] : bufh[(l + 1) & 1];
                __hip_atomic_store(dst + (size_t)(m * 16 + r) * 128 + n * 4 + c4, q,
                                   __ATOMIC_RELAXED, __HIP_MEMORY_SCOPE_AGENT);
            }
            __builtin_amdgcn_s_waitcnt(0);
            __syncthreads();
            if (tid == 0)
                __hip_atomic_store(fl + n, (unsigned)(l + 1),
                                   __ATOMIC_RELAXED, __HIP_MEMORY_SCOPE_AGENT);
        }
        if (tid == 0)
            __hip_atomic_fetch_add(bar + 256, 1u, __ATOMIC_RELAXED, __HIP_MEMORY_SCOPE_AGENT);
    }

    // -------- handoff: wait for all 256 encoder blocks; final h in hS0 --------
    if (tid == 0) {
        while (__hip_atomic_load(bar + 256, __ATOMIC_RELAXED, __HIP_MEMORY_SCOPE_AGENT) < 256u)
            __builtin_amdgcn_s_sleep(2);
    }
    __syncthreads();

    // =============== SDE + decoder: m2 = bid>>3 (64 rows), n2 = bid&7 (64 units) ===============
    const int m2 = bid >> 3, n2 = bid & 7;
    const int rt = wv & 3, nc = wv >> 2;        // wave -> (row-tile, n-half)
    const int r0g = m2 * 64;                    // row base in 2048-space
    const int u0 = n2 * 64, u0c = n2 * 16;      // unit base (shorts / u64-cols)
    const int s = m2 >> 1, b0 = (m2 & 1) * 64;  // sample / batch base
    unsigned* uf = bar + 320 + m2 * 8;
    unsigned* hf = bar + 576 + m2 * 8;
    u64* hDh[2] = {hD0h, hD1h};
    u64* hDl[2] = {hD0l, hD1l};

    // initial stage: h_enc rows b0..b0+64 (broadcast over samples) -> hA64
    stage64(hS0h, hS0l, b0, hA64hi, hA64lo, tid);
    __syncthreads();

    float hreg[2][4];
    #pragma unroll
    for (int nt = 0; nt < 2; ++nt)
        #pragma unroll
        for (int v = 0; v < 4; ++v) {
            int cc = u0 + nc * 32 + nt * 16 + l15;
            hreg[nt][v] = bf2f(hA64hi[rt][g4 * 4 + v][cc]) + bf2f(hA64lo[rt][g4 * 4 + v][cc]);
        }

    float b1v[2], b2v[2], gbv[2];
    #pragma unroll
    for (int nt = 0; nt < 2; ++nt) {
        int u = u0 + nc * 32 + nt * 16 + l15;
        b1v[nt] = fb1[u]; b2v[nt] = fb2[u]; gbv[nt] = gb[u];
    }
    const float dt = (float)NF / (float)NSTEP;
    const float sqdt = sqrtf(dt);

    #pragma unroll 1
    for (int st = 0; st < NSTEP; ++st) {
        // ---- phase A: au = h W1^T, ag = h gW^T (hA64 holds h_st) ----
        f32x4 au[2] = {zz, zz}, ag[2] = {zz, zz};
        #pragma unroll 2
        for (int kt = 0; kt < 16; ++kt) {
            bf16x8 ah = *(const bf16x8*)&hA64hi[rt][l15][kt * 32 + g4 * 8];
            bf16x8 al = *(const bf16x8*)&hA64lo[rt][l15][kt * 32 + g4 * 8];
            #pragma unroll
            for (int nt = 0; nt < 2; ++nt) {
                int ntg = n2 * 4 + nc * 2 + nt;
                au[nt] = mfma3(ah, al, w1_p + ((size_t)(ntg * 16 + kt) * 64 + lane) * 16, au[nt]);
                ag[nt] = mfma3(ah, al, gw_p + ((size_t)(ntg * 16 + kt) * 64 + lane) * 16, ag[nt]);
            }
        }
        // noise prefetch (HBM latency hides under the exchange)
        float nz[2][4];
        #pragma unroll
        for (int nt = 0; nt < 2; ++nt)
            #pragma unroll
            for (int v = 0; v < 4; ++v)
                nz[nt][v] = noise[((size_t)(s * NSTEP + st) * NB + b0 + rt * 16 + g4 * 4 + v) * HD
                                  + u0 + nc * 32 + nt * 16 + l15];
        #pragma unroll
        for (int nt = 0; nt < 2; ++nt)
            #pragma unroll
            for (int v = 0; v < 4; ++v) {
                unsigned short hi, lo;
                split_bf(tanhf(au[nt][v] + b1v[nt]), hi, lo);
                uShi[rt * 16 + g4 * 4 + v][nc * 32 + nt * 16 + l15] = hi;
                uSlo[rt * 16 + g4 * 4 + v][nc * 32 + nt * 16 + l15] = lo;
            }
        __syncthreads();
        publish64(uPh, uPl, r0g, u0c, uShi, uSlo, tid);
        sigval(uf + n2, (unsigned)(st + 1), tid);
        poll8(uf, (unsigned)(st + 1), wv, lane);
        stage64(uPh, uPl, r0g, hA64hi, hA64lo, tid);   // hA64 := u (phase-A reads done)
        __syncthreads();
        // ---- phase B: af = u W2^T; h update ----
        f32x4 af[2] = {zz, zz};
        #pragma unroll 2
        for (int kt = 0; kt < 16; ++kt) {
            bf16x8 uh = *(const bf16x8*)&hA64hi[rt][l15][kt * 32 + g4 * 8];
            bf16x8 ul = *(const bf16x8*)&hA64lo[rt][l15][kt * 32 + g4 * 8];
            #pragma unroll
            for (int nt = 0; nt < 2; ++nt) {
                int ntg = n2 * 4 + nc * 2 + nt;
                af[nt] = mfma3(uh, ul, w2_p + ((size_t)(ntg * 16 + kt) * 64 + lane) * 16, af[nt]);
            }
        }
        #pragma unroll
        for (int nt = 0; nt < 2; ++nt)
            #pragma unroll
            for (int v = 0; v < 4; ++v) {
                float gg = softp(ag[nt][v] + gbv[nt]);
                hreg[nt][v] += (af[nt][v] + b2v[nt]) * dt + gg * sqdt * nz[nt][v];
                unsigned short hi, lo;
                split_bf(hreg[nt][v], hi, lo);
                uShi[rt * 16 + g4 * 4 + v][nc * 32 + nt * 16 + l15] = hi;
                uSlo[rt * 16 + g4 * 4 + v][nc * 32 + nt * 16 + l15] = lo;
            }
        __syncthreads();
        publish64(hDh[(st + 1) & 1], hDl[(st + 1) & 1], r0g, u0c, uShi, uSlo, tid);
        sigval(hf + n2, (unsigned)(st + 1), tid);
        poll8(hf, (unsigned)(st + 1), wv, lane);
        stage64(hDh[(st + 1) & 1], hDl[(st + 1) & 1], r0g, hA64hi, hA64lo, tid);  // h_{st+1}
        __syncthreads();
    }

    // =============== decoder GRU + out-proj ===============
    float crv[2], czv[2], binv[2], bhnv[2];
    #pragma unroll
    for (int nt = 0; nt < 2; ++nt) {
        int u = u0 + nc * 32 + nt * 16 + l15;
        crv[nt] = dbih[u] + dbhh[u];
        czv[nt] = dbih[HD + u] + dbhh[HD + u];
        binv[nt] = dbih[2 * HD + u];
        bhnv[nt] = dbhh[2 * HD + u];
    }
    float obias[2] = {0.f, 0.f};
    if (n2 == 0 && wv < 4) {
        obias[0] = outb[l15];
        obias[1] = outb[16 + l15];
    }

    #pragma unroll 1
    for (int j = 0; j <= NF; ++j) {
        // hA64 holds h_j^dec (flag 23+j). out_{j-1} = proj(h_j) for j>=1.
        if (j >= 1 && n2 == 0 && wv < 4) {
            f32x4 ao[2] = {zz, zz};
            #pragma unroll 2
            for (int kt = 0; kt < 16; ++kt) {
                bf16x8 ah = *(const bf16x8*)&hA64hi[rt][l15][kt * 32 + g4 * 8];
                bf16x8 al = *(const bf16x8*)&hA64lo[rt][l15][kt * 32 + g4 * 8];
                #pragma unroll
                for (int nt = 0; nt < 2; ++nt)
                    ao[nt] = mfma3(ah, al, outw_p + ((size_t)(nt * 16 + kt) * 64 + lane) * 16, ao[nt]);
            }
            #pragma unroll
            for (int nt = 0; nt < 2; ++nt)
                #pragma unroll
                for (int v = 0; v < 4; ++v) {
                    int b = b0 + rt * 16 + g4 * 4 + v;
                    out[(((size_t)s * NB + b) * NI + nt * 16 + l15) * NF + (j - 1)]
                        = ao[nt][v] + obias[nt];
                }
        }
        if (j == NF) break;
        f32x4 ar[2] = {zz, zz}, az[2] = {zz, zz}, anh[2] = {zz, zz};
        #pragma unroll 2
        for (int kt = 0; kt < 16; ++kt) {
            bf16x8 ah = *(const bf16x8*)&hA64hi[rt][l15][kt * 32 + g4 * 8];
            bf16x8 al = *(const bf16x8*)&hA64lo[rt][l15][kt * 32 + g4 * 8];
            #pragma unroll
            for (int nt = 0; nt < 2; ++nt) {
                int ntg = n2 * 4 + nc * 2 + nt;
                ar[nt]  = mfma3(ah, al, dwhh_p + ((size_t)((ntg) * 16 + kt) * 64 + lane) * 16, ar[nt]);
                az[nt]  = mfma3(ah, al, dwhh_p + ((size_t)((32 + ntg) * 16 + kt) * 64 + lane) * 16, az[nt]);
                anh[nt] = mfma3(ah, al, dwhh_p + ((size_t)((64 + ntg) * 16 + kt) * 64 + lane) * 16, anh[nt]);
            }
        }
        #pragma unroll
        for (int nt = 0; nt < 2; ++nt)
            #pragma unroll
            for (int v = 0; v < 4; ++v) {
                float r = sigm(ar[nt][v] + crv[nt]);
                float z = sigm(az[nt][v] + czv[nt]);
                float nn2 = tanhf(binv[nt] + r * (anh[nt][v] + bhnv[nt]));
                hreg[nt][v] = (1.f - z) * nn2 + z * hreg[nt][v];
                unsigned short hi, lo;
                split_bf(hreg[nt][v], hi, lo);
                uShi[rt * 16 + g4 * 4 + v][nc * 32 + nt * 16 + l15] = hi;
                uSlo[rt * 16 + g4 * 4 + v][nc * 32 + nt * 16 + l15] = lo;
            }
        __syncthreads();
        publish64(hDh[(NSTEP + j + 1) & 1], hDl[(NSTEP + j + 1) & 1], r0g, u0c, uShi, uSlo, tid);
        sigval(hf + n2, (unsigned)(NSTEP + j + 1), tid);
        poll8(hf, (unsigned)(NSTEP + j + 1), wv, lane);
        stage64(hDh[(NSTEP + j + 1) & 1], hDl[(NSTEP + j + 1) & 1], r0g, hA64hi, hA64lo, tid);
        __syncthreads();
    }
}

extern "C" void kernel_launch(void* const* d_in, const int* in_sizes, int n_in,
                              void* d_out, int out_size, void* d_ws, size_t ws_size,
                              hipStream_t stream) {
    const float* x       = (const float*)d_in[0];
    const float* noise   = (const float*)d_in[1];
    const float* enc_Wih = (const float*)d_in[2];
    const float* enc_Whh = (const float*)d_in[3];
    const float* enc_bih = (const float*)d_in[4];
    const float* enc_bhh = (const float*)d_in[5];
    const float* f_W1    = (const float*)d_in[6];
    const float* f_b1    = (const float*)d_in[7];
    const float* f_W2    = (const float*)d_in[8];
    const float* f_b2    = (const float*)d_in[9];
    const float* g_W     = (const float*)d_in[10];
    const float* g_b     = (const float*)d_in[11];
    const float* dec_Whh = (const float*)d_in[13];
    const float* dec_bih = (const float*)d_in[14];
    const float* dec_bhh = (const float*)d_in[15];
    const float* out_W   = (const float*)d_in[16];
    const float* out_b   = (const float*)d_in[17];
    float* out = (float*)d_out;

    char* ws = (char*)d_ws;
    unsigned short* whh_p  = (unsigned short*)(ws + 0);          // 3 MB
    unsigned short* wih_p  = (unsigned short*)(ws + 3145728);    // 192 KB
    unsigned short* w1_p   = (unsigned short*)(ws + 3342336);    // 1 MB
    unsigned short* w2_p   = (unsigned short*)(ws + 4390912);    // 1 MB
    unsigned short* gw_p   = (unsigned short*)(ws + 5439488);    // 1 MB
    unsigned short* dwhh_p = (unsigned short*)(ws + 6488064);    // 3 MB
    unsigned short* outw_p = (unsigned short*)(ws + 9633792);    // 64 KB
    unsigned short* xhi    = (unsigned short*)(ws + 9699328);    // 768 KB
    unsigned short* xlo    = (unsigned short*)(ws + 10485760);   // 768 KB
    u64*            hS0h   = (u64*)(ws + 11272192);              // 128 KB [128][128]
    u64*            hS0l   = (u64*)(ws + 11403264);              // 128 KB
    u64*            hS1h   = (u64*)(ws + 11534336);              // 128 KB
    u64*            hS1l   = (u64*)(ws + 11665408);              // 128 KB
    unsigned*       bar    = (unsigned*)(ws + 11796480);         // 4 KB flags
    u64*            uPh    = (u64*)(ws + 11800576);              // 2 MB [2048][128]
    u64*            uPl    = (u64*)(ws + 13897728);              // 2 MB
    u64*            hD0h   = (u64*)(ws + 15994880);              // 2 MB
    u64*            hD0l   = (u64*)(ws + 18092032);              // 2 MB
    u64*            hD1h   = (u64*)(ws + 20189184);              // 2 MB
    u64*            hD1l   = (u64*)(ws + 22286336);              // 2 MB

    // zero h(0) encoder state + all flags
    hipMemsetAsync(ws + 11272192, 0, 262144, stream);
    hipMemsetAsync(ws + 11796480, 0, 4096, stream);

    pack_w<<<384, 256, 0, stream>>>(enc_Whh, whh_p, 3 * HD, HD);
    pack_w<<<24, 256, 0, stream>>>(enc_Wih, wih_p, 3 * HD, NI);
    pack_w<<<128, 256, 0, stream>>>(f_W1, w1_p, HD, HD);
    pack_w<<<128, 256, 0, stream>>>(f_W2, w2_p, HD, HD);
    pack_w<<<128, 256, 0, stream>>>(g_W, gw_p, HD, HD);
    pack_w<<<384, 256, 0, stream>>>(dec_Whh, dwhh_p, 3 * HD, HD);
    pack_w<<<8, 256, 0, stream>>>(out_W, outw_p, NI, HD);
    pack_x<<<48, 256, 0, stream>>>(x, xhi, xlo);

    void* args[] = {
        (void*)&xhi, (void*)&xlo, (void*)&wih_p, (void*)&whh_p,
        (void*)&w1_p, (void*)&w2_p, (void*)&gw_p, (void*)&dwhh_p, (void*)&outw_p,
        (void*)&enc_bih, (void*)&enc_bhh, (void*)&f_b1, (void*)&f_b2,
        (void*)&g_b, (void*)&dec_bih, (void*)&dec_bhh, (void*)&out_b,
        (void*)&noise,
        (void*)&hS0h, (void*)&hS0l, (void*)&hS1h, (void*)&hS1l,
        (void*)&uPh, (void*)&uPl, (void*)&hD0h, (void*)&hD0l, (void*)&hD1h, (void*)&hD1l,
        (void*)&out, (void*)&bar
    };
    hipLaunchCooperativeKernel((void*)coop_all, dim3(256), dim3(512), args, 0, stream);
}

// Round 7
// 1714.696 us; speedup vs baseline: 3.6032x; 1.0859x over previous
//
#include <hip/hip_runtime.h>
#include <math.h>

typedef __bf16 bf16x8 __attribute__((ext_vector_type(8)));
typedef float f32x4 __attribute__((ext_vector_type(4)));
typedef unsigned int u32x4 __attribute__((ext_vector_type(4)));
typedef unsigned long long u64;

#define HD 512
#define NB 128
#define NI 32
#define NL 96
#define NS 16
#define NF 24
#define NSTEP 23
#define PAD 520   // LDS A-tile row stride in shorts (1040 B, 16B-aligned rows)

#define MFMA16(a,b,c) __builtin_amdgcn_mfma_f32_16x16x32_bf16(a,b,c,0,0,0)

__device__ __forceinline__ unsigned short f2bf(float f) {
    union { float f; unsigned u; } v; v.f = f;
    unsigned r = v.u + 0x7fffu + ((v.u >> 16) & 1u);
    return (unsigned short)(r >> 16);
}
__device__ __forceinline__ float bf2f(unsigned short h) {
    union { unsigned u; float f; } v; v.u = ((unsigned)h) << 16;
    return v.f;
}
__device__ __forceinline__ void split_bf(float v, unsigned short& hi, unsigned short& lo) {
    unsigned short h = f2bf(v);
    hi = h;
    lo = f2bf(v - bf2f(h));
}
__device__ __forceinline__ float sigm(float x) { return 1.0f / (1.0f + __expf(-x)); }
__device__ __forceinline__ float softp(float x) {
    return fmaxf(x, 0.0f) + log1pf(__expf(-fabsf(x)));
}
__device__ __forceinline__ bf16x8 ld8(const unsigned short* p) {
    return *reinterpret_cast<const bf16x8*>(p);
}
// split-bf16 3-term product: (ahi+alo)*(bhi+blo) ~= ahi*bhi + alo*bhi + ahi*blo
__device__ __forceinline__ f32x4 mfma3(bf16x8 ahi, bf16x8 alo, const unsigned short* bp, f32x4 c) {
    bf16x8 bhi = ld8(bp);
    bf16x8 blo = ld8(bp + 8);
    c = MFMA16(ahi, bhi, c);
    c = MFMA16(alo, bhi, c);
    c = MFMA16(ahi, blo, c);
    return c;
}

// 16B coherent-bypass load (sc0: skip L1, sc1: skip L2) -- state buffers are
// never L2-cached, so stale-line hazards can't exist. Issue many, then one
// vmcnt(0) + sched_barrier before consuming (rule: asm loads aren't tracked).
__device__ __forceinline__ void ld16i(const void* p, u32x4& d) {
    asm volatile("global_load_dwordx4 %0, %1, off sc0 sc1"
                 : "=&v"(d) : "v"(p) : "memory");
}
__device__ __forceinline__ void ldfence() {
    asm volatile("s_waitcnt vmcnt(0)" ::: "memory");
    __builtin_amdgcn_sched_barrier(0);
}

// ---- proven exchange primitives (rounds 5-6) ----
__device__ __forceinline__ void sigval(unsigned* slot, unsigned val, int tid) {
    __builtin_amdgcn_s_waitcnt(0);
    __syncthreads();
    if (tid == 0)
        __hip_atomic_store(slot, val, __ATOMIC_RELAXED, __HIP_MEMORY_SCOPE_AGENT);
}
// ONE wave polls the group's 4 flags (round-1 lesson: never more than one wave)
__device__ __forceinline__ void poll4(const unsigned* f, unsigned tgt, int wv, int lane) {
    if (wv == 0) {
        for (;;) {
            unsigned v = __hip_atomic_load(f + (lane & 3), __ATOMIC_RELAXED, __HIP_MEMORY_SCOPE_AGENT);
            if (__all((int)(v >= tgt))) break;
            __builtin_amdgcn_s_sleep(2);
        }
    }
    __syncthreads();
}
// bulk stage 32 rows x 512 cols (both split planes) global -> LDS A-tiles
__device__ __forceinline__ void stage32(const u64* sh, const u64* sl, int r0,
        unsigned short (*Ahi)[16][PAD], unsigned short (*Alo)[16][PAD], int tid) {
    u32x4 th[4], tl[4];
    #pragma unroll
    for (int k = 0; k < 4; ++k) {
        int idx = k * 512 + tid;          // 0..2047 -> 32 rows x 64 16B-cols
        int r = idx >> 6, c8 = idx & 63;
        ld16i(sh + (size_t)(r0 + r) * 128 + c8 * 2, th[k]);
        ld16i(sl + (size_t)(r0 + r) * 128 + c8 * 2, tl[k]);
    }
    ldfence();
    #pragma unroll
    for (int k = 0; k < 4; ++k) {
        int idx = k * 512 + tid;
        int r = idx >> 6, c8 = idx & 63;
        *(u32x4*)&Ahi[r >> 4][r & 15][c8 * 8] = th[k];
        *(u32x4*)&Alo[r >> 4][r & 15][c8 * 8] = tl[k];
    }
}
// publish block's 32x128 slice LDS -> global planes (8B agent stores, light side)
__device__ __forceinline__ void publish32(u64* dh, u64* dl, int r0, int u0c,
        unsigned short (*Bhi)[136], unsigned short (*Blo)[136], int tid) {
    #pragma unroll
    for (int rep = 0; rep < 4; ++rep) {
        int idx = rep * 512 + tid;          // 0..2047 = 2 planes x 32 rows x 32 u64cols
        int pl = idx >> 10, e = idx & 1023;
        int r = e >> 5, c = e & 31;
        u64 q = pl ? *(const u64*)&Blo[r][c * 4] : *(const u64*)&Bhi[r][c * 4];
        u64* dst = (pl ? dl : dh) + (size_t)(r0 + r) * 128 + u0c + c;
        __hip_atomic_store(dst, q, __ATOMIC_RELAXED, __HIP_MEMORY_SCOPE_AGENT);
    }
}

// ---------- prep: pack W[N][K] fp32 -> split bf16 B-fragments ----------
__global__ void pack_w(const float* __restrict__ W, unsigned short* __restrict__ Wp,
                       int N, int K) {
    int idx = blockIdx.x * 256 + threadIdx.x;
    int total = (N / 16) * (K / 32) * 64;
    if (idx >= total) return;
    int lane = idx & 63;
    int t2 = idx >> 6;
    int KT = K / 32;
    int kt = t2 % KT, nt = t2 / KT;
    const float* src = W + (size_t)(nt * 16 + (lane & 15)) * K + kt * 32 + (lane >> 4) * 8;
    unsigned short* dst = Wp + (size_t)idx * 16;
    #pragma unroll
    for (int j = 0; j < 8; ++j) split_bf(src[j], dst[j], dst[8 + j]);
}

// ---------- prep: x[B][I][L] fp32 -> xhi/xlo [L][B][I] bf16 ----------
__global__ void pack_x(const float* __restrict__ x, unsigned short* __restrict__ xhi,
                       unsigned short* __restrict__ xlo) {
    int idx = blockIdx.x * 256 + threadIdx.x;
    if (idx >= NL * NB) return;
    int b = idx % NB, l = idx / NB;
    size_t base = (size_t)(l * NB + b) * NI;
    #pragma unroll
    for (int i = 0; i < NI; ++i)
        split_bf(x[((size_t)b * NI + i) * NL + l], xhi[base + i], xlo[base + i]);
}

// =================== fused kernel ===================
// Encoder (round-5, proven): 256 blocks = 8 m-groups x 32 n-slices.
// SDE+decoder: 256 blocks = 64 row-groups (32 rows of S*B=2048) x 4 unit-slices
// (128 units). Round-6 lesson: exchange READ traffic = 4MB x U per exchange --
// U=8 gave 32 MB @ ~1.8 TB/s = the bottleneck. U=4 halves it; weight slices
// (1.5 MB SDE+dec total per XCD) stay L2-resident. Staging via 16B sc0/sc1
// asm loads (one vmcnt fence per batch).
__global__ __launch_bounds__(512, 2) void coop_all(
    const unsigned short* __restrict__ xhi, const unsigned short* __restrict__ xlo,
    const unsigned short* __restrict__ wih_p, const unsigned short* __restrict__ whh_p,
    const unsigned short* __restrict__ w1_p, const unsigned short* __restrict__ w2_p,
    const unsigned short* __restrict__ gw_p, const unsigned short* __restrict__ dwhh_p,
    const unsigned short* __restrict__ outw_p,
    const float* __restrict__ ebih, const float* __restrict__ ebhh,
    const float* __restrict__ fb1, const float* __restrict__ fb2,
    const float* __restrict__ gb, const float* __restrict__ dbih,
    const float* __restrict__ dbhh, const float* __restrict__ outb,
    const float* __restrict__ noise,
    u64* hS0h, u64* hS0l, u64* hS1h, u64* hS1l,
    u64* uPh, u64* uPl, u64* hD0h, u64* hD0l, u64* hD1h, u64* hD1l,
    float* out, unsigned* bar)
{
    const int bid = blockIdx.x;
    const int tid = threadIdx.x, lane = tid & 63, wv = tid >> 6;
    const int l15 = lane & 15, g4 = lane >> 4;
    const f32x4 zz = {0.f, 0.f, 0.f, 0.f};

    // LDS overlay: SDE phase [hA32 65KB | uS 17KB] = 83968 B total; encoder
    // phase [pred 32KB | ehA 33KB | S 1KB] overlays the same bytes.
    __shared__ __align__(16) unsigned char SM[83968];
    auto hA32hi = reinterpret_cast<unsigned short (*)[16][PAD]>(SM);           // [2][16][PAD]
    auto hA32lo = reinterpret_cast<unsigned short (*)[16][PAD]>(SM + 33280);
    auto uShi   = reinterpret_cast<unsigned short (*)[136]>(SM + 66560);       // [32][136]
    auto uSlo   = reinterpret_cast<unsigned short (*)[136]>(SM + 75264);
    auto pred   = reinterpret_cast<float (*)[8][16][16]>(SM);                  // [4][8][16][16]
    auto ehAhi  = reinterpret_cast<unsigned short (*)[PAD]>(SM + 32768);       // [16][PAD]
    auto ehAlo  = reinterpret_cast<unsigned short (*)[PAD]>(SM + 49408);
    auto Shi    = reinterpret_cast<unsigned short (*)[16]>(SM + 66048);        // [16][16]
    auto Slo    = reinterpret_cast<unsigned short (*)[16]>(SM + 66560);

    u64* bufh[2] = {hS0h, hS1h};
    u64* bufl[2] = {hS0l, hS1l};

    // =============== encoder: m = bid>>5 (16 rows), n = bid&31 (16 units) ===============
    {
        const int m = bid >> 5, n = bid & 31;
        unsigned* fl = bar + m * 32;
        float cr = 0.f, cz = 0.f, binx = 0.f, bhnn = 0.f, hcell = 0.f;
        const int crow = tid >> 4, cunit = tid & 15;
        if (tid < 256) {
            int u = n * 16 + cunit;
            cr = ebih[u] + ebhh[u];
            cz = ebih[HD + u] + ebhh[HD + u];
            binx = ebih[2 * HD + u];
            bhnn = ebhh[2 * HD + u];
        }
        #pragma unroll 1
        for (int l = 0; l < NL; ++l) {
            bf16x8 axh, axl;
            if (wv == 0) {
                size_t xb = ((size_t)l * NB + m * 16 + l15) * NI + g4 * 8;
                axh = ld8(xhi + xb);
                axl = ld8(xlo + xb);
            }
            if (l > 0) {
                if (wv == 0) {
                    for (;;) {
                        unsigned v = __hip_atomic_load(fl + (lane & 31),
                                     __ATOMIC_RELAXED, __HIP_MEMORY_SCOPE_AGENT);
                        if (__all((int)(v >= (unsigned)l))) break;
                        __builtin_amdgcn_s_sleep(2);
                    }
                }
                __syncthreads();
            }
            {   // bulk read rows m*16..+16 of buf[l&1] -> LDS, 16B bypass loads
                const u64* sh = bufh[l & 1];
                const u64* sl = bufl[l & 1];
                u32x4 qh[2], ql[2];
                #pragma unroll
                for (int rep = 0; rep < 2; ++rep) {
                    int idx = rep * 512 + tid;          // 0..1023: 16 rows x 64 16B-cols
                    int r = idx >> 6, c8 = idx & 63;
                    ld16i(sh + (size_t)(m * 16 + r) * 128 + c8 * 2, qh[rep]);
                    ld16i(sl + (size_t)(m * 16 + r) * 128 + c8 * 2, ql[rep]);
                }
                ldfence();
                #pragma unroll
                for (int rep = 0; rep < 2; ++rep) {
                    int idx = rep * 512 + tid;
                    int r = idx >> 6, c8 = idx & 63;
                    *(u32x4*)&ehAhi[r][c8 * 8] = qh[rep];
                    *(u32x4*)&ehAlo[r][c8 * 8] = ql[rep];
                }
            }
            __syncthreads();
            f32x4 pr = zz, pz = zz, pnh = zz, pnx = zz;
            if (wv == 0) {
                pr  = mfma3(axh, axl, wih_p + ((size_t)(0 * 32 + n) * 64 + lane) * 16, pr);
                pz  = mfma3(axh, axl, wih_p + ((size_t)(1 * 32 + n) * 64 + lane) * 16, pz);
                pnx = mfma3(axh, axl, wih_p + ((size_t)(2 * 32 + n) * 64 + lane) * 16, pnx);
            }
            #pragma unroll
            for (int kk = 0; kk < 2; ++kk) {
                int kt = wv * 2 + kk;
                bf16x8 ah = *(const bf16x8*)&ehAhi[l15][kt * 32 + g4 * 8];
                bf16x8 al = *(const bf16x8*)&ehAlo[l15][kt * 32 + g4 * 8];
                pr  = mfma3(ah, al, whh_p + ((size_t)((0 * 32 + n) * 16 + kt) * 64 + lane) * 16, pr);
                pz  = mfma3(ah, al, whh_p + ((size_t)((1 * 32 + n) * 16 + kt) * 64 + lane) * 16, pz);
                pnh = mfma3(ah, al, whh_p + ((size_t)((2 * 32 + n) * 16 + kt) * 64 + lane) * 16, pnh);
            }
            #pragma unroll
            for (int v = 0; v < 4; ++v) {
                pred[0][wv][g4 * 4 + v][l15] = pr[v];
                pred[1][wv][g4 * 4 + v][l15] = pz[v];
                pred[2][wv][g4 * 4 + v][l15] = pnh[v];
                if (wv == 0) pred[3][0][g4 * 4 + v][l15] = pnx[v];
            }
            __syncthreads();
            if (tid < 256) {
                float ar = 0.f, az = 0.f, anh_ = 0.f;
                #pragma unroll
                for (int w = 0; w < 8; ++w) {
                    ar += pred[0][w][crow][cunit];
                    az += pred[1][w][crow][cunit];
                    anh_ += pred[2][w][crow][cunit];
                }
                float anx_ = pred[3][0][crow][cunit];
                float r = sigm(ar + cr);
                float z = sigm(az + cz);
                float nn = tanhf(anx_ + binx + r * (anh_ + bhnn));
                hcell = (1.f - z) * nn + z * hcell;
                unsigned short hi, lo;
                split_bf(hcell, hi, lo);
                Shi[crow][cunit] = hi;
                Slo[crow][cunit] = lo;
            }
            __syncthreads();
            if (tid < 128) {
                int p = tid >> 6, t = tid & 63;
                int r = t >> 2, c4 = t & 3;
                u64 q = p ? *(const u64*)&Slo[r][c4 * 4] : *(const u64*)&Shi[r][c4 * 4];
                u64* dst = p ? bufl[(l + 1) & 1] : bufh[(l + 1) & 1];
                __hip_atomic_store(dst + (size_t)(m * 16 + r) * 128 + n * 4 + c4, q,
                                   __ATOMIC_RELAXED, __HIP_MEMORY_SCOPE_AGENT);
            }
            __builtin_amdgcn_s_waitcnt(0);
            __syncthreads();
            if (tid == 0)
                __hip_atomic_store(fl + n, (unsigned)(l + 1),
                                   __ATOMIC_RELAXED, __HIP_MEMORY_SCOPE_AGENT);
        }
        if (tid == 0)
            __hip_atomic_fetch_add(bar + 256, 1u, __ATOMIC_RELAXED, __HIP_MEMORY_SCOPE_AGENT);
    }

    // -------- handoff: wait for all 256 encoder blocks; final h in hS0 --------
    if (tid == 0) {
        while (__hip_atomic_load(bar + 256, __ATOMIC_RELAXED, __HIP_MEMORY_SCOPE_AGENT) < 256u)
            __builtin_amdgcn_s_sleep(2);
    }
    __syncthreads();

    // ===== SDE + decoder: m2 = bid>>2 (32 rows), n2 = bid&3 (128 units) =====
    const int m2 = bid >> 2, n2 = bid & 3;
    const int rt = wv & 1, nc = wv >> 1;        // wave -> (row-tile of 16, unit-quarter of 32)
    const int r0g = m2 * 32;                    // row base in 2048-space
    const int u0 = n2 * 128, u0c = n2 * 32;     // unit base (shorts / u64-cols)
    const int s = m2 >> 2, b0 = (m2 & 3) * 32;  // sample / batch base
    unsigned* uf = bar + 320 + m2 * 4;
    unsigned* hf = bar + 576 + m2 * 4;
    u64* hDh[2] = {hD0h, hD1h};
    u64* hDl[2] = {hD0l, hD1l};

    // initial stage: h_enc rows b0..b0+32 (broadcast over samples) -> hA32
    stage32(hS0h, hS0l, b0, hA32hi, hA32lo, tid);
    __syncthreads();

    float hreg[2][4];
    #pragma unroll
    for (int nt = 0; nt < 2; ++nt)
        #pragma unroll
        for (int v = 0; v < 4; ++v) {
            int cc = u0 + nc * 32 + nt * 16 + l15;
            hreg[nt][v] = bf2f(hA32hi[rt][g4 * 4 + v][cc]) + bf2f(hA32lo[rt][g4 * 4 + v][cc]);
        }

    float b1v[2], b2v[2], gbv[2];
    #pragma unroll
    for (int nt = 0; nt < 2; ++nt) {
        int u = u0 + nc * 32 + nt * 16 + l15;
        b1v[nt] = fb1[u]; b2v[nt] = fb2[u]; gbv[nt] = gb[u];
    }
    const float dt = (float)NF / (float)NSTEP;
    const float sqdt = sqrtf(dt);

    #pragma unroll 1
    for (int st = 0; st < NSTEP; ++st) {
        // ---- phase A: au = h W1^T, ag = h gW^T (hA32 holds h_st) ----
        f32x4 au[2] = {zz, zz}, ag[2] = {zz, zz};
        #pragma unroll 2
        for (int kt = 0; kt < 16; ++kt) {
            bf16x8 ah = *(const bf16x8*)&hA32hi[rt][l15][kt * 32 + g4 * 8];
            bf16x8 al = *(const bf16x8*)&hA32lo[rt][l15][kt * 32 + g4 * 8];
            #pragma unroll
            for (int nt = 0; nt < 2; ++nt) {
                int ntg = n2 * 8 + nc * 2 + nt;
                au[nt] = mfma3(ah, al, w1_p + ((size_t)(ntg * 16 + kt) * 64 + lane) * 16, au[nt]);
                ag[nt] = mfma3(ah, al, gw_p + ((size_t)(ntg * 16 + kt) * 64 + lane) * 16, ag[nt]);
            }
        }
        // noise prefetch (HBM latency hides under the exchange)
        float nz[2][4];
        #pragma unroll
        for (int nt = 0; nt < 2; ++nt)
            #pragma unroll
            for (int v = 0; v < 4; ++v)
                nz[nt][v] = noise[((size_t)(s * NSTEP + st) * NB + b0 + rt * 16 + g4 * 4 + v) * HD
                                  + u0 + nc * 32 + nt * 16 + l15];
        #pragma unroll
        for (int nt = 0; nt < 2; ++nt)
            #pragma unroll
            for (int v = 0; v < 4; ++v) {
                unsigned short hi, lo;
                split_bf(tanhf(au[nt][v] + b1v[nt]), hi, lo);
                uShi[rt * 16 + g4 * 4 + v][nc * 32 + nt * 16 + l15] = hi;
                uSlo[rt * 16 + g4 * 4 + v][nc * 32 + nt * 16 + l15] = lo;
            }
        __syncthreads();
        publish32(uPh, uPl, r0g, u0c, uShi, uSlo, tid);
        sigval(uf + n2, (unsigned)(st + 1), tid);
        poll4(uf, (unsigned)(st + 1), wv, lane);
        stage32(uPh, uPl, r0g, hA32hi, hA32lo, tid);   // hA32 := u (phase-A reads done)
        __syncthreads();
        // ---- phase B: af = u W2^T; h update ----
        f32x4 af[2] = {zz, zz};
        #pragma unroll 2
        for (int kt = 0; kt < 16; ++kt) {
            bf16x8 uh = *(const bf16x8*)&hA32hi[rt][l15][kt * 32 + g4 * 8];
            bf16x8 ul = *(const bf16x8*)&hA32lo[rt][l15][kt * 32 + g4 * 8];
            #pragma unroll
            for (int nt = 0; nt < 2; ++nt) {
                int ntg = n2 * 8 + nc * 2 + nt;
                af[nt] = mfma3(uh, ul, w2_p + ((size_t)(ntg * 16 + kt) * 64 + lane) * 16, af[nt]);
            }
        }
        #pragma unroll
        for (int nt = 0; nt < 2; ++nt)
            #pragma unroll
            for (int v = 0; v < 4; ++v) {
                float gg = softp(ag[nt][v] + gbv[nt]);
                hreg[nt][v] += (af[nt][v] + b2v[nt]) * dt + gg * sqdt * nz[nt][v];
                unsigned short hi, lo;
                split_bf(hreg[nt][v], hi, lo);
                uShi[rt * 16 + g4 * 4 + v][nc * 32 + nt * 16 + l15] = hi;
                uSlo[rt * 16 + g4 * 4 + v][nc * 32 + nt * 16 + l15] = lo;
            }
        __syncthreads();
        publish32(hDh[(st + 1) & 1], hDl[(st + 1) & 1], r0g, u0c, uShi, uSlo, tid);
        sigval(hf + n2, (unsigned)(st + 1), tid);
        poll4(hf, (unsigned)(st + 1), wv, lane);
        stage32(hDh[(st + 1) & 1], hDl[(st + 1) & 1], r0g, hA32hi, hA32lo, tid);  // h_{st+1}
        __syncthreads();
    }

    // =============== decoder GRU + out-proj ===============
    float crv[2], czv[2], binv[2], bhnv[2];
    #pragma unroll
    for (int nt = 0; nt < 2; ++nt) {
        int u = u0 + nc * 32 + nt * 16 + l15;
        crv[nt] = dbih[u] + dbhh[u];
        czv[nt] = dbih[HD + u] + dbhh[HD + u];
        binv[nt] = dbih[2 * HD + u];
        bhnv[nt] = dbhh[2 * HD + u];
    }
    float obias[2] = {0.f, 0.f};
    if (n2 == 0 && nc == 0) {
        obias[0] = outb[l15];
        obias[1] = outb[16 + l15];
    }

    #pragma unroll 1
    for (int j = 0; j <= NF; ++j) {
        // hA32 holds h_j^dec. out_{j-1} = proj(h_j) for j>=1 (units 0..31 ->
        // blocks n2==0, waves nc==0 i.e. wv 0..1 covering both row tiles).
        if (j >= 1 && n2 == 0 && nc == 0) {
            f32x4 ao[2] = {zz, zz};
            #pragma unroll 2
            for (int kt = 0; kt < 16; ++kt) {
                bf16x8 ah = *(const bf16x8*)&hA32hi[rt][l15][kt * 32 + g4 * 8];
                bf16x8 al = *(const bf16x8*)&hA32lo[rt][l15][kt * 32 + g4 * 8];
                #pragma unroll
                for (int nt = 0; nt < 2; ++nt)
                    ao[nt] = mfma3(ah, al, outw_p + ((size_t)(nt * 16 + kt) * 64 + lane) * 16, ao[nt]);
            }
            #pragma unroll
            for (int nt = 0; nt < 2; ++nt)
                #pragma unroll
                for (int v = 0; v < 4; ++v) {
                    int b = b0 + rt * 16 + g4 * 4 + v;
                    out[(((size_t)s * NB + b) * NI + nt * 16 + l15) * NF + (j - 1)]
                        = ao[nt][v] + obias[nt];
                }
        }
        if (j == NF) break;
        f32x4 ar[2] = {zz, zz}, az[2] = {zz, zz}, anh[2] = {zz, zz};
        #pragma unroll 2
        for (int kt = 0; kt < 16; ++kt) {
            bf16x8 ah = *(const bf16x8*)&hA32hi[rt][l15][kt * 32 + g4 * 8];
            bf16x8 al = *(const bf16x8*)&hA32lo[rt][l15][kt * 32 + g4 * 8];
            #pragma unroll
            for (int nt = 0; nt < 2; ++nt) {
                int ntg = n2 * 8 + nc * 2 + nt;
                ar[nt]  = mfma3(ah, al, dwhh_p + ((size_t)((ntg) * 16 + kt) * 64 + lane) * 16, ar[nt]);
                az[nt]  = mfma3(ah, al, dwhh_p + ((size_t)((32 + ntg) * 16 + kt) * 64 + lane) * 16, az[nt]);
                anh[nt] = mfma3(ah, al, dwhh_p + ((size_t)((64 + ntg) * 16 + kt) * 64 + lane) * 16, anh[nt]);
            }
        }
        #pragma unroll
        for (int nt = 0; nt < 2; ++nt)
            #pragma unroll
            for (int v = 0; v < 4; ++v) {
                float r = sigm(ar[nt][v] + crv[nt]);
                float z = sigm(az[nt][v] + czv[nt]);
                float nn2 = tanhf(binv[nt] + r * (anh[nt][v] + bhnv[nt]));
                hreg[nt][v] = (1.f - z) * nn2 + z * hreg[nt][v];
                unsigned short hi, lo;
                split_bf(hreg[nt][v], hi, lo);
                uShi[rt * 16 + g4 * 4 + v][nc * 32 + nt * 16 + l15] = hi;
                uSlo[rt * 16 + g4 * 4 + v][nc * 32 + nt * 16 + l15] = lo;
            }
        __syncthreads();
        publish32(hDh[(NSTEP + j + 1) & 1], hDl[(NSTEP + j + 1) & 1], r0g, u0c, uShi, uSlo, tid);
        sigval(hf + n2, (unsigned)(NSTEP + j + 1), tid);
        poll4(hf, (unsigned)(NSTEP + j + 1), wv, lane);
        stage32(hDh[(NSTEP + j + 1) & 1], hDl[(NSTEP + j + 1) & 1], r0g, hA32hi, hA32lo, tid);
        __syncthreads();
    }
}

extern "C" void kernel_launch(void* const* d_in, const int* in_sizes, int n_in,
                              void* d_out, int out_size, void* d_ws, size_t ws_size,
                              hipStream_t stream) {
    const float* x       = (const float*)d_in[0];
    const float* noise   = (const float*)d_in[1];
    const float* enc_Wih = (const float*)d_in[2];
    const float* enc_Whh = (const float*)d_in[3];
    const float* enc_bih = (const float*)d_in[4];
    const float* enc_bhh = (const float*)d_in[5];
    const float* f_W1    = (const float*)d_in[6];
    const float* f_b1    = (const float*)d_in[7];
    const float* f_W2    = (const float*)d_in[8];
    const float* f_b2    = (const float*)d_in[9];
    const float* g_W     = (const float*)d_in[10];
    const float* g_b     = (const float*)d_in[11];
    const float* dec_Whh = (const float*)d_in[13];
    const float* dec_bih = (const float*)d_in[14];
    const float* dec_bhh = (const float*)d_in[15];
    const float* out_W   = (const float*)d_in[16];
    const float* out_b   = (const float*)d_in[17];
    float* out = (float*)d_out;

    char* ws = (char*)d_ws;
    unsigned short* whh_p  = (unsigned short*)(ws + 0);          // 3 MB
    unsigned short* wih_p  = (unsigned short*)(ws + 3145728);    // 192 KB
    unsigned short* w1_p   = (unsigned short*)(ws + 3342336);    // 1 MB
    unsigned short* w2_p   = (unsigned short*)(ws + 4390912);    // 1 MB
    unsigned short* gw_p   = (unsigned short*)(ws + 5439488);    // 1 MB
    unsigned short* dwhh_p = (unsigned short*)(ws + 6488064);    // 3 MB
    unsigned short* outw_p = (unsigned short*)(ws + 9633792);    // 64 KB
    unsigned short* xhi    = (unsigned short*)(ws + 9699328);    // 768 KB
    unsigned short* xlo    = (unsigned short*)(ws + 10485760);   // 768 KB
    u64*            hS0h   = (u64*)(ws + 11272192);              // 128 KB [128][128]
    u64*            hS0l   = (u64*)(ws + 11403264);              // 128 KB
    u64*            hS1h   = (u64*)(ws + 11534336);              // 128 KB
    u64*            hS1l   = (u64*)(ws + 11665408);              // 128 KB
    unsigned*       bar    = (unsigned*)(ws + 11796480);         // 4 KB flags
    u64*            uPh    = (u64*)(ws + 11800576);              // 2 MB [2048][128]
    u64*            uPl    = (u64*)(ws + 13897728);              // 2 MB
    u64*            hD0h   = (u64*)(ws + 15994880);              // 2 MB
    u64*            hD0l   = (u64*)(ws + 18092032);              // 2 MB
    u64*            hD1h   = (u64*)(ws + 20189184);              // 2 MB
    u64*            hD1l   = (u64*)(ws + 22286336);              // 2 MB

    // zero h(0) encoder state + all flags
    hipMemsetAsync(ws + 11272192, 0, 262144, stream);
    hipMemsetAsync(ws + 11796480, 0, 4096, stream);

    pack_w<<<384, 256, 0, stream>>>(enc_Whh, whh_p, 3 * HD, HD);
    pack_w<<<24, 256, 0, stream>>>(enc_Wih, wih_p, 3 * HD, NI);
    pack_w<<<128, 256, 0, stream>>>(f_W1, w1_p, HD, HD);
    pack_w<<<128, 256, 0, stream>>>(f_W2, w2_p, HD, HD);
    pack_w<<<128, 256, 0, stream>>>(g_W, gw_p, HD, HD);
    pack_w<<<384, 256, 0, stream>>>(dec_Whh, dwhh_p, 3 * HD, HD);
    pack_w<<<8, 256, 0, stream>>>(out_W, outw_p, NI, HD);
    pack_x<<<48, 256, 0, stream>>>(x, xhi, xlo);

    void* args[] = {
        (void*)&xhi, (void*)&xlo, (void*)&wih_p, (void*)&whh_p,
        (void*)&w1_p, (void*)&w2_p, (void*)&gw_p, (void*)&dwhh_p, (void*)&outw_p,
        (void*)&enc_bih, (void*)&enc_bhh, (void*)&f_b1, (void*)&f_b2,
        (void*)&g_b, (void*)&dec_bih, (void*)&dec_bhh, (void*)&out_b,
        (void*)&noise,
        (void*)&hS0h, (void*)&hS0l, (void*)&hS1h, (void*)&hS1l,
        (void*)&uPh, (void*)&uPl, (void*)&hD0h, (void*)&hD0l, (void*)&hD1h, (void*)&hD1l,
        (void*)&out, (void*)&bar
    };
    hipLaunchCooperativeKernel((void*)coop_all, dim3(256), dim3(512), args, 0, stream);
}

// Round 9
// 1695.593 us; speedup vs baseline: 3.6438x; 1.0113x over previous
//
#include <hip/hip_runtime.h>
#include <math.h>

typedef __bf16 bf16x8 __attribute__((ext_vector_type(8)));
typedef float f32x4 __attribute__((ext_vector_type(4)));
typedef unsigned int u32x4 __attribute__((ext_vector_type(4)));
typedef unsigned long long u64;

#define HD 512
#define NB 128
#define NI 32
#define NL 96
#define NS 16
#define NF 24
#define NSTEP 23
#define PAD 520   // LDS A-tile row stride in shorts (1040 B, 16B-aligned rows)

#define MFMA16(a,b,c) __builtin_amdgcn_mfma_f32_16x16x32_bf16(a,b,c,0,0,0)

__device__ __forceinline__ unsigned short f2bf(float f) {
    union { float f; unsigned u; } v; v.f = f;
    unsigned r = v.u + 0x7fffu + ((v.u >> 16) & 1u);
    return (unsigned short)(r >> 16);
}
__device__ __forceinline__ float bf2f(unsigned short h) {
    union { unsigned u; float f; } v; v.u = ((unsigned)h) << 16;
    return v.f;
}
__device__ __forceinline__ void split_bf(float v, unsigned short& hi, unsigned short& lo) {
    unsigned short h = f2bf(v);
    hi = h;
    lo = f2bf(v - bf2f(h));
}
__device__ __forceinline__ float sigm(float x) { return 1.0f / (1.0f + __expf(-x)); }
__device__ __forceinline__ float softp(float x) {
    return fmaxf(x, 0.0f) + log1pf(__expf(-fabsf(x)));
}
__device__ __forceinline__ bf16x8 ld8(const unsigned short* p) {
    return *reinterpret_cast<const bf16x8*>(p);
}
// split-bf16 3-term product: (ahi+alo)*(bhi+blo) ~= ahi*bhi + alo*bhi + ahi*blo
__device__ __forceinline__ f32x4 mfma3(bf16x8 ahi, bf16x8 alo, const unsigned short* bp, f32x4 c) {
    bf16x8 bhi = ld8(bp);
    bf16x8 blo = ld8(bp + 8);
    c = MFMA16(ahi, bhi, c);
    c = MFMA16(alo, bhi, c);
    c = MFMA16(ahi, blo, c);
    return c;
}

// 16B coherent-bypass load (sc0+sc1). State buffers are never L2-cached, so
// stale-line hazards can't exist. Issue many, then one vmcnt(0)+sched_barrier.
__device__ __forceinline__ void ld16i(const void* p, u32x4& d) {
    asm volatile("global_load_dwordx4 %0, %1, off sc0 sc1"
                 : "=&v"(d) : "v"(p) : "memory");
}
__device__ __forceinline__ void ldfence() {
    asm volatile("s_waitcnt vmcnt(0)" ::: "memory");
    __builtin_amdgcn_sched_barrier(0);
}

// ---- proven exchange primitives (rounds 5-7) ----
__device__ __forceinline__ void sigval(unsigned* slot, unsigned val, int tid) {
    __builtin_amdgcn_s_waitcnt(0);
    __syncthreads();
    if (tid == 0)
        __hip_atomic_store(slot, val, __ATOMIC_RELAXED, __HIP_MEMORY_SCOPE_AGENT);
}
// ONE wave polls the group's 4 flags (round-1 lesson: never more than one wave)
__device__ __forceinline__ void poll4(const unsigned* f, unsigned tgt, int wv, int lane) {
    if (wv == 0) {
        for (;;) {
            unsigned v = __hip_atomic_load(f + (lane & 3), __ATOMIC_RELAXED, __HIP_MEMORY_SCOPE_AGENT);
            if (__all((int)(v >= tgt))) break;
            __builtin_amdgcn_s_sleep(1);
        }
    }
    __syncthreads();
}
// bulk stage 32 rows x 512 cols (both split planes) global -> LDS A-tiles
__device__ __forceinline__ void stage32(const u64* sh, const u64* sl, int r0,
        unsigned short (*Ahi)[16][PAD], unsigned short (*Alo)[16][PAD], int tid) {
    u32x4 th[4], tl[4];
    #pragma unroll
    for (int k = 0; k < 4; ++k) {
        int idx = k * 512 + tid;          // 0..2047 -> 32 rows x 64 16B-cols
        int r = idx >> 6, c8 = idx & 63;
        ld16i(sh + (size_t)(r0 + r) * 128 + c8 * 2, th[k]);
        ld16i(sl + (size_t)(r0 + r) * 128 + c8 * 2, tl[k]);
    }
    ldfence();
    #pragma unroll
    for (int k = 0; k < 4; ++k) {
        int idx = k * 512 + tid;
        int r = idx >> 6, c8 = idx & 63;
        *(u32x4*)&Ahi[r >> 4][r & 15][c8 * 8] = th[k];
        *(u32x4*)&Alo[r >> 4][r & 15][c8 * 8] = tl[k];
    }
}
// stage ONLY the 3 peer slices (48 KB): own slice never round-trips the fabric
__device__ __forceinline__ void stage_peers(const u64* sh, const u64* sl, int r0, int n2,
        unsigned short (*Ahi)[16][PAD], unsigned short (*Alo)[16][PAD], int tid) {
    u32x4 t[6];
    #pragma unroll
    for (int k = 0; k < 6; ++k) {
        int it = k * 512 + tid;            // 0..3071 = 2 planes x 3 peers x 32r x 16 16B-cols
        int pl = (it >= 1536) ? 1 : 0;
        int e = it - pl * 1536;
        int p = e >> 9;
        int w = e & 511;
        int r = w >> 4, c16 = w & 15;
        int q = (n2 + 1 + p) & 3;
        const u64* src = (pl ? sl : sh) + (size_t)(r0 + r) * 128 + q * 32 + c16 * 2;
        ld16i(src, t[k]);
    }
    ldfence();
    #pragma unroll
    for (int k = 0; k < 6; ++k) {
        int it = k * 512 + tid;
        int pl = (it >= 1536) ? 1 : 0;
        int e = it - pl * 1536;
        int p = e >> 9;
        int w = e & 511;
        int r = w >> 4, c16 = w & 15;
        int q = (n2 + 1 + p) & 3;
        unsigned short (*A)[16][PAD] = pl ? Alo : Ahi;
        *(u32x4*)&A[r >> 4][r & 15][q * 128 + c16 * 8] = t[k];
    }
}
// LDS->LDS: copy own 32x128-unit slice from uS into hA32's own columns
__device__ __forceinline__ void own_copy(unsigned short (*Shi_)[136], unsigned short (*Slo_)[136],
        int u0s, unsigned short (*Ahi)[16][PAD], unsigned short (*Alo)[16][PAD], int tid) {
    #pragma unroll
    for (int k = 0; k < 2; ++k) {
        int it = k * 512 + tid;           // 0..1023 = 2 planes x 32r x 16 16B-cols
        int pl = (it >= 512) ? 1 : 0;
        int w = it & 511;
        int r = w >> 4, c16 = w & 15;
        u32x4 v = pl ? *(const u32x4*)&Slo_[r][c16 * 8] : *(const u32x4*)&Shi_[r][c16 * 8];
        unsigned short (*A)[16][PAD] = pl ? Alo : Ahi;
        *(u32x4*)&A[r >> 4][r & 15][u0s + c16 * 8] = v;
    }
}
// publish block's 32x128 slice LDS -> global planes (8B agent stores)
__device__ __forceinline__ void publish32(u64* dh, u64* dl, int r0, int u0c,
        unsigned short (*Bhi)[136], unsigned short (*Blo)[136], int tid) {
    #pragma unroll
    for (int rep = 0; rep < 4; ++rep) {
        int idx = rep * 512 + tid;          // 0..2047 = 2 planes x 32 rows x 32 u64cols
        int pl = idx >> 10, e = idx & 1023;
        int r = e >> 5, c = e & 31;
        u64 q = pl ? *(const u64*)&Blo[r][c * 4] : *(const u64*)&Bhi[r][c * 4];
        u64* dst = (pl ? dl : dh) + (size_t)(r0 + r) * 128 + u0c + c;
        __hip_atomic_store(dst, q, __ATOMIC_RELAXED, __HIP_MEMORY_SCOPE_AGENT);
    }
}

// ---------- prep: pack W[N][K] fp32 -> split bf16 B-fragments ----------
__global__ void pack_w(const float* __restrict__ W, unsigned short* __restrict__ Wp,
                       int N, int K) {
    int idx = blockIdx.x * 256 + threadIdx.x;
    int total = (N / 16) * (K / 32) * 64;
    if (idx >= total) return;
    int lane = idx & 63;
    int t2 = idx >> 6;
    int KT = K / 32;
    int kt = t2 % KT, nt = t2 / KT;
    const float* src = W + (size_t)(nt * 16 + (lane & 15)) * K + kt * 32 + (lane >> 4) * 8;
    unsigned short* dst = Wp + (size_t)idx * 16;
    #pragma unroll
    for (int j = 0; j < 8; ++j) split_bf(src[j], dst[j], dst[8 + j]);
}

// ---------- prep: x[B][I][L] fp32 -> xhi/xlo [L][B][I] bf16 ----------
__global__ void pack_x(const float* __restrict__ x, unsigned short* __restrict__ xhi,
                       unsigned short* __restrict__ xlo) {
    int idx = blockIdx.x * 256 + threadIdx.x;
    if (idx >= NL * NB) return;
    int b = idx % NB, l = idx / NB;
    size_t base = (size_t)(l * NB + b) * NI;
    #pragma unroll
    for (int i = 0; i < NI; ++i)
        split_bf(x[((size_t)b * NI + i) * NL + l], xhi[base + i], xlo[base + i]);
}

// =================== fused kernel ===================
// Round-7 structure (proven): encoder 8x32, SDE+dec 64 row-groups x 4 slices,
// agent-scope exchanges. Round-9 deltas (exchange-latency overlap):
//  - stage only PEER slices (48KB not 64KB); own slice LDS-copied (own_copy)
//  - phase-B own-kt MFMAs run between sigval and poll (hide peers' publish)
//  - own_copy of h runs between sigval and poll
__global__ __launch_bounds__(512, 2) void coop_all(
    const unsigned short* __restrict__ xhi, const unsigned short* __restrict__ xlo,
    const unsigned short* __restrict__ wih_p, const unsigned short* __restrict__ whh_p,
    const unsigned short* __restrict__ w1_p, const unsigned short* __restrict__ w2_p,
    const unsigned short* __restrict__ gw_p, const unsigned short* __restrict__ dwhh_p,
    const unsigned short* __restrict__ outw_p,
    const float* __restrict__ ebih, const float* __restrict__ ebhh,
    const float* __restrict__ fb1, const float* __restrict__ fb2,
    const float* __restrict__ gb, const float* __restrict__ dbih,
    const float* __restrict__ dbhh, const float* __restrict__ outb,
    const float* __restrict__ noise,
    u64* hS0h, u64* hS0l, u64* hS1h, u64* hS1l,
    u64* uPh, u64* uPl, u64* hD0h, u64* hD0l, u64* hD1h, u64* hD1l,
    float* out, unsigned* bar)
{
    const int bid = blockIdx.x;
    const int tid = threadIdx.x, lane = tid & 63, wv = tid >> 6;
    const int l15 = lane & 15, g4 = lane >> 4;
    const f32x4 zz = {0.f, 0.f, 0.f, 0.f};

    // LDS overlay: SDE phase [hA32 65KB | uS 17KB]; encoder overlays same bytes.
    __shared__ __align__(16) unsigned char SM[83968];
    auto hA32hi = reinterpret_cast<unsigned short (*)[16][PAD]>(SM);           // [2][16][PAD]
    auto hA32lo = reinterpret_cast<unsigned short (*)[16][PAD]>(SM + 33280);
    auto uShi   = reinterpret_cast<unsigned short (*)[136]>(SM + 66560);       // [32][136]
    auto uSlo   = reinterpret_cast<unsigned short (*)[136]>(SM + 75264);
    auto pred   = reinterpret_cast<float (*)[8][16][16]>(SM);                  // [4][8][16][16]
    auto ehAhi  = reinterpret_cast<unsigned short (*)[PAD]>(SM + 32768);       // [16][PAD]
    auto ehAlo  = reinterpret_cast<unsigned short (*)[PAD]>(SM + 49408);
    auto Shi    = reinterpret_cast<unsigned short (*)[16]>(SM + 66048);        // [16][16]
    auto Slo    = reinterpret_cast<unsigned short (*)[16]>(SM + 66560);

    u64* bufh[2] = {hS0h, hS1h};
    u64* bufl[2] = {hS0l, hS1l};

    // =============== encoder: m = bid>>5 (16 rows), n = bid&31 (16 units) ===============
    {
        const int m = bid >> 5, n = bid & 31;
        unsigned* fl = bar + m * 32;
        float cr = 0.f, cz = 0.f, binx = 0.f, bhnn = 0.f, hcell = 0.f;
        const int crow = tid >> 4, cunit = tid & 15;
        if (tid < 256) {
            int u = n * 16 + cunit;
            cr = ebih[u] + ebhh[u];
            cz = ebih[HD + u] + ebhh[HD + u];
            binx = ebih[2 * HD + u];
            bhnn = ebhh[2 * HD + u];
        }
        #pragma unroll 1
        for (int l = 0; l < NL; ++l) {
            bf16x8 axh, axl;
            if (wv == 0) {
                size_t xb = ((size_t)l * NB + m * 16 + l15) * NI + g4 * 8;
                axh = ld8(xhi + xb);
                axl = ld8(xlo + xb);
            }
            if (l > 0) {
                if (wv == 0) {
                    for (;;) {
                        unsigned v = __hip_atomic_load(fl + (lane & 31),
                                     __ATOMIC_RELAXED, __HIP_MEMORY_SCOPE_AGENT);
                        if (__all((int)(v >= (unsigned)l))) break;
                        __builtin_amdgcn_s_sleep(1);
                    }
                }
                __syncthreads();
            }
            {   // bulk read rows m*16..+16 of buf[l&1] -> LDS, 16B bypass loads
                const u64* sh = bufh[l & 1];
                const u64* sl = bufl[l & 1];
                u32x4 qh[2], ql[2];
                #pragma unroll
                for (int rep = 0; rep < 2; ++rep) {
                    int idx = rep * 512 + tid;          // 0..1023: 16 rows x 64 16B-cols
                    int r = idx >> 6, c8 = idx & 63;
                    ld16i(sh + (size_t)(m * 16 + r) * 128 + c8 * 2, qh[rep]);
                    ld16i(sl + (size_t)(m * 16 + r) * 128 + c8 * 2, ql[rep]);
                }
                ldfence();
                #pragma unroll
                for (int rep = 0; rep < 2; ++rep) {
                    int idx = rep * 512 + tid;
                    int r = idx >> 6, c8 = idx & 63;
                    *(u32x4*)&ehAhi[r][c8 * 8] = qh[rep];
                    *(u32x4*)&ehAlo[r][c8 * 8] = ql[rep];
                }
            }
            __syncthreads();
            f32x4 pr = zz, pz = zz, pnh = zz, pnx = zz;
            if (wv == 0) {
                pr  = mfma3(axh, axl, wih_p + ((size_t)(0 * 32 + n) * 64 + lane) * 16, pr);
                pz  = mfma3(axh, axl, wih_p + ((size_t)(1 * 32 + n) * 64 + lane) * 16, pz);
                pnx = mfma3(axh, axl, wih_p + ((size_t)(2 * 32 + n) * 64 + lane) * 16, pnx);
            }
            #pragma unroll
            for (int kk = 0; kk < 2; ++kk) {
                int kt = wv * 2 + kk;
                bf16x8 ah = *(const bf16x8*)&ehAhi[l15][kt * 32 + g4 * 8];
                bf16x8 al = *(const bf16x8*)&ehAlo[l15][kt * 32 + g4 * 8];
                pr  = mfma3(ah, al, whh_p + ((size_t)((0 * 32 + n) * 16 + kt) * 64 + lane) * 16, pr);
                pz  = mfma3(ah, al, whh_p + ((size_t)((1 * 32 + n) * 16 + kt) * 64 + lane) * 16, pz);
                pnh = mfma3(ah, al, whh_p + ((size_t)((2 * 32 + n) * 16 + kt) * 64 + lane) * 16, pnh);
            }
            #pragma unroll
            for (int v = 0; v < 4; ++v) {
                pred[0][wv][g4 * 4 + v][l15] = pr[v];
                pred[1][wv][g4 * 4 + v][l15] = pz[v];
                pred[2][wv][g4 * 4 + v][l15] = pnh[v];
                if (wv == 0) pred[3][0][g4 * 4 + v][l15] = pnx[v];
            }
            __syncthreads();
            if (tid < 256) {
                float ar = 0.f, az = 0.f, anh_ = 0.f;
                #pragma unroll
                for (int w = 0; w < 8; ++w) {
                    ar += pred[0][w][crow][cunit];
                    az += pred[1][w][crow][cunit];
                    anh_ += pred[2][w][crow][cunit];
                }
                float anx_ = pred[3][0][crow][cunit];
                float r = sigm(ar + cr);
                float z = sigm(az + cz);
                float nn = tanhf(anx_ + binx + r * (anh_ + bhnn));
                hcell = (1.f - z) * nn + z * hcell;
                unsigned short hi, lo;
                split_bf(hcell, hi, lo);
                Shi[crow][cunit] = hi;
                Slo[crow][cunit] = lo;
            }
            __syncthreads();
            if (tid < 128) {
                int p = tid >> 6, t = tid & 63;
                int r = t >> 2, c4 = t & 3;
                u64 q = p ? *(const u64*)&Slo[r][c4 * 4] : *(const u64*)&Shi[r][c4 * 4];
                u64* dst = p ? bufl[(l + 1) & 1] : bufh[(l + 1) & 1];
                __hip_atomic_store(dst + (size_t)(m * 16 + r) * 128 + n * 4 + c4, q,
                                   __ATOMIC_RELAXED, __HIP_MEMORY_SCOPE_AGENT);
            }
            __builtin_amdgcn_s_waitcnt(0);
            __syncthreads();
            if (tid == 0)
                __hip_atomic_store(fl + n, (unsigned)(l + 1),
                                   __ATOMIC_RELAXED, __HIP_MEMORY_SCOPE_AGENT);
        }
        if (tid == 0)
            __hip_atomic_fetch_add(bar + 256, 1u, __ATOMIC_RELAXED, __HIP_MEMORY_SCOPE_AGENT);
    }

    // -------- handoff: wait for all 256 encoder blocks; final h in hS0 --------
    if (tid == 0) {
        while (__hip_atomic_load(bar + 256, __ATOMIC_RELAXED, __HIP_MEMORY_SCOPE_AGENT) < 256u)
            __builtin_amdgcn_s_sleep(2);
    }
    __syncthreads();

    // ===== SDE + decoder: m2 = bid>>2 (32 rows), n2 = bid&3 (128 units) =====
    const int m2 = bid >> 2, n2 = bid & 3;
    const int rt = wv & 1, nc = wv >> 1;        // wave -> (row-tile of 16, unit-quarter of 32)
    const int r0g = m2 * 32;                    // row base in 2048-space
    const int u0 = n2 * 128, u0c = n2 * 32;     // unit base (shorts / u64-cols)
    const int s = m2 >> 2, b0 = (m2 & 3) * 32;  // sample / batch base
    unsigned* uf = bar + 320 + m2 * 4;
    unsigned* hf = bar + 576 + m2 * 4;
    u64* hDh[2] = {hD0h, hD1h};
    u64* hDl[2] = {hD0l, hD1l};

    // initial stage: h_enc rows b0..b0+32 (broadcast over samples) -> hA32
    stage32(hS0h, hS0l, b0, hA32hi, hA32lo, tid);
    __syncthreads();

    float hreg[2][4];
    #pragma unroll
    for (int nt = 0; nt < 2; ++nt)
        #pragma unroll
        for (int v = 0; v < 4; ++v) {
            int cc = u0 + nc * 32 + nt * 16 + l15;
            hreg[nt][v] = bf2f(hA32hi[rt][g4 * 4 + v][cc]) + bf2f(hA32lo[rt][g4 * 4 + v][cc]);
        }

    float b1v[2], b2v[2], gbv[2];
    #pragma unroll
    for (int nt = 0; nt < 2; ++nt) {
        int u = u0 + nc * 32 + nt * 16 + l15;
        b1v[nt] = fb1[u]; b2v[nt] = fb2[u]; gbv[nt] = gb[u];
    }
    const float dt = (float)NF / (float)NSTEP;
    const float sqdt = sqrtf(dt);

    #pragma unroll 1
    for (int st = 0; st < NSTEP; ++st) {
        // ---- phase A: au = h W1^T, ag = h gW^T (hA32 holds h_st) ----
        f32x4 au[2] = {zz, zz}, ag[2] = {zz, zz};
        #pragma unroll 2
        for (int kt = 0; kt < 16; ++kt) {
            bf16x8 ah = *(const bf16x8*)&hA32hi[rt][l15][kt * 32 + g4 * 8];
            bf16x8 al = *(const bf16x8*)&hA32lo[rt][l15][kt * 32 + g4 * 8];
            #pragma unroll
            for (int nt = 0; nt < 2; ++nt) {
                int ntg = n2 * 8 + nc * 2 + nt;
                au[nt] = mfma3(ah, al, w1_p + ((size_t)(ntg * 16 + kt) * 64 + lane) * 16, au[nt]);
                ag[nt] = mfma3(ah, al, gw_p + ((size_t)(ntg * 16 + kt) * 64 + lane) * 16, ag[nt]);
            }
        }
        // noise prefetch (HBM latency hides under the exchange)
        float nz[2][4];
        #pragma unroll
        for (int nt = 0; nt < 2; ++nt)
            #pragma unroll
            for (int v = 0; v < 4; ++v)
                nz[nt][v] = noise[((size_t)(s * NSTEP + st) * NB + b0 + rt * 16 + g4 * 4 + v) * HD
                                  + u0 + nc * 32 + nt * 16 + l15];
        #pragma unroll
        for (int nt = 0; nt < 2; ++nt)
            #pragma unroll
            for (int v = 0; v < 4; ++v) {
                unsigned short hi, lo;
                split_bf(tanhf(au[nt][v] + b1v[nt]), hi, lo);
                uShi[rt * 16 + g4 * 4 + v][nc * 32 + nt * 16 + l15] = hi;
                uSlo[rt * 16 + g4 * 4 + v][nc * 32 + nt * 16 + l15] = lo;
            }
        __syncthreads();
        publish32(uPh, uPl, r0g, u0c, uShi, uSlo, tid);
        sigval(uf + n2, (unsigned)(st + 1), tid);
        // ---- own-kt phase-B MFMAs from uS while peers publish (latency hiding) ----
        f32x4 af[2] = {zz, zz};
        #pragma unroll
        for (int kk = 0; kk < 4; ++kk) {
            int kt = n2 * 4 + kk;
            bf16x8 uh = *(const bf16x8*)&uShi[rt * 16 + l15][kk * 32 + g4 * 8];
            bf16x8 ul = *(const bf16x8*)&uSlo[rt * 16 + l15][kk * 32 + g4 * 8];
            #pragma unroll
            for (int nt = 0; nt < 2; ++nt) {
                int ntg = n2 * 8 + nc * 2 + nt;
                af[nt] = mfma3(uh, ul, w2_p + ((size_t)(ntg * 16 + kt) * 64 + lane) * 16, af[nt]);
            }
        }
        poll4(uf, (unsigned)(st + 1), wv, lane);
        stage_peers(uPh, uPl, r0g, n2, hA32hi, hA32lo, tid);   // peer u -> hA32
        __syncthreads();
        // ---- phase B: peer kts ----
        #pragma unroll 2
        for (int kt = 0; kt < 16; ++kt) {
            if ((kt >> 2) == n2) continue;
            bf16x8 uh = *(const bf16x8*)&hA32hi[rt][l15][kt * 32 + g4 * 8];
            bf16x8 ul = *(const bf16x8*)&hA32lo[rt][l15][kt * 32 + g4 * 8];
            #pragma unroll
            for (int nt = 0; nt < 2; ++nt) {
                int ntg = n2 * 8 + nc * 2 + nt;
                af[nt] = mfma3(uh, ul, w2_p + ((size_t)(ntg * 16 + kt) * 64 + lane) * 16, af[nt]);
            }
        }
        #pragma unroll
        for (int nt = 0; nt < 2; ++nt)
            #pragma unroll
            for (int v = 0; v < 4; ++v) {
                float gg = softp(ag[nt][v] + gbv[nt]);
                hreg[nt][v] += (af[nt][v] + b2v[nt]) * dt + gg * sqdt * nz[nt][v];
                unsigned short hi, lo;
                split_bf(hreg[nt][v], hi, lo);
                uShi[rt * 16 + g4 * 4 + v][nc * 32 + nt * 16 + l15] = hi;
                uSlo[rt * 16 + g4 * 4 + v][nc * 32 + nt * 16 + l15] = lo;
            }
        __syncthreads();
        publish32(hDh[(st + 1) & 1], hDl[(st + 1) & 1], r0g, u0c, uShi, uSlo, tid);
        sigval(hf + n2, (unsigned)(st + 1), tid);
        own_copy(uShi, uSlo, u0, hA32hi, hA32lo, tid);          // own h -> hA32 (pre-poll)
        poll4(hf, (unsigned)(st + 1), wv, lane);
        stage_peers(hDh[(st + 1) & 1], hDl[(st + 1) & 1], r0g, n2, hA32hi, hA32lo, tid);
        __syncthreads();
    }

    // =============== decoder GRU + out-proj ===============
    float crv[2], czv[2], binv[2], bhnv[2];
    #pragma unroll
    for (int nt = 0; nt < 2; ++nt) {
        int u = u0 + nc * 32 + nt * 16 + l15;
        crv[nt] = dbih[u] + dbhh[u];
        czv[nt] = dbih[HD + u] + dbhh[HD + u];
        binv[nt] = dbih[2 * HD + u];
        bhnv[nt] = dbhh[2 * HD + u];
    }
    float obias[2] = {0.f, 0.f};
    if (n2 == 0 && nc == 0) {
        obias[0] = outb[l15];
        obias[1] = outb[16 + l15];
    }

    #pragma unroll 1
    for (int j = 0; j <= NF; ++j) {
        // hA32 holds h_j^dec. out_{j-1} = proj(h_j) for j>=1.
        if (j >= 1 && n2 == 0 && nc == 0) {
            f32x4 ao[2] = {zz, zz};
            #pragma unroll 2
            for (int kt = 0; kt < 16; ++kt) {
                bf16x8 ah = *(const bf16x8*)&hA32hi[rt][l15][kt * 32 + g4 * 8];
                bf16x8 al = *(const bf16x8*)&hA32lo[rt][l15][kt * 32 + g4 * 8];
                #pragma unroll
                for (int nt = 0; nt < 2; ++nt)
                    ao[nt] = mfma3(ah, al, outw_p + ((size_t)(nt * 16 + kt) * 64 + lane) * 16, ao[nt]);
            }
            #pragma unroll
            for (int nt = 0; nt < 2; ++nt)
                #pragma unroll
                for (int v = 0; v < 4; ++v) {
                    int b = b0 + rt * 16 + g4 * 4 + v;
                    out[(((size_t)s * NB + b) * NI + nt * 16 + l15) * NF + (j - 1)]
                        = ao[nt][v] + obias[nt];
                }
        }
        if (j == NF) break;
        f32x4 ar[2] = {zz, zz}, az[2] = {zz, zz}, anh[2] = {zz, zz};
        #pragma unroll 2
        for (int kt = 0; kt < 16; ++kt) {
            bf16x8 ah = *(const bf16x8*)&hA32hi[rt][l15][kt * 32 + g4 * 8];
            bf16x8 al = *(const bf16x8*)&hA32lo[rt][l15][kt * 32 + g4 * 8];
            #pragma unroll
            for (int nt = 0; nt < 2; ++nt) {
                int ntg = n2 * 8 + nc * 2 + nt;
                ar[nt]  = mfma3(ah, al, dwhh_p + ((size_t)((ntg) * 16 + kt) * 64 + lane) * 16, ar[nt]);
                az[nt]  = mfma3(ah, al, dwhh_p + ((size_t)((32 + ntg) * 16 + kt) * 64 + lane) * 16, az[nt]);
                anh[nt] = mfma3(ah, al, dwhh_p + ((size_t)((64 + ntg) * 16 + kt) * 64 + lane) * 16, anh[nt]);
            }
        }
        #pragma unroll
        for (int nt = 0; nt < 2; ++nt)
            #pragma unroll
            for (int v = 0; v < 4; ++v) {
                float r = sigm(ar[nt][v] + crv[nt]);
                float z = sigm(az[nt][v] + czv[nt]);
                float nn2 = tanhf(binv[nt] + r * (anh[nt][v] + bhnv[nt]));
                hreg[nt][v] = (1.f - z) * nn2 + z * hreg[nt][v];
                unsigned short hi, lo;
                split_bf(hreg[nt][v], hi, lo);
                uShi[rt * 16 + g4 * 4 + v][nc * 32 + nt * 16 + l15] = hi;
                uSlo[rt * 16 + g4 * 4 + v][nc * 32 + nt * 16 + l15] = lo;
            }
        __syncthreads();
        publish32(hDh[(NSTEP + j + 1) & 1], hDl[(NSTEP + j + 1) & 1], r0g, u0c, uShi, uSlo, tid);
        sigval(hf + n2, (unsigned)(NSTEP + j + 1), tid);
        own_copy(uShi, uSlo, u0, hA32hi, hA32lo, tid);          // own h -> hA32 (pre-poll)
        poll4(hf, (unsigned)(NSTEP + j + 1), wv, lane);
        stage_peers(hDh[(NSTEP + j + 1) & 1], hDl[(NSTEP + j + 1) & 1], r0g, n2, hA32hi, hA32lo, tid);
        __syncthreads();
    }
}

extern "C" void kernel_launch(void* const* d_in, const int* in_sizes, int n_in,
                              void* d_out, int out_size, void* d_ws, size_t ws_size,
                              hipStream_t stream) {
    const float* x       = (const float*)d_in[0];
    const float* noise   = (const float*)d_in[1];
    const float* enc_Wih = (const float*)d_in[2];
    const float* enc_Whh = (const float*)d_in[3];
    const float* enc_bih = (const float*)d_in[4];
    const float* enc_bhh = (const float*)d_in[5];
    const float* f_W1    = (const float*)d_in[6];
    const float* f_b1    = (const float*)d_in[7];
    const float* f_W2    = (const float*)d_in[8];
    const float* f_b2    = (const float*)d_in[9];
    const float* g_W     = (const float*)d_in[10];
    const float* g_b     = (const float*)d_in[11];
    const float* dec_Whh = (const float*)d_in[13];
    const float* dec_bih = (const float*)d_in[14];
    const float* dec_bhh = (const float*)d_in[15];
    const float* out_W   = (const float*)d_in[16];
    const float* out_b   = (const float*)d_in[17];
    float* out = (float*)d_out;

    char* ws = (char*)d_ws;
    unsigned short* whh_p  = (unsigned short*)(ws + 0);          // 3 MB
    unsigned short* wih_p  = (unsigned short*)(ws + 3145728);    // 192 KB
    unsigned short* w1_p   = (unsigned short*)(ws + 3342336);    // 1 MB
    unsigned short* w2_p   = (unsigned short*)(ws + 4390912);    // 1 MB
    unsigned short* gw_p   = (unsigned short*)(ws + 5439488);    // 1 MB
    unsigned short* dwhh_p = (unsigned short*)(ws + 6488064);    // 3 MB
    unsigned short* outw_p = (unsigned short*)(ws + 9633792);    // 64 KB
    unsigned short* xhi    = (unsigned short*)(ws + 9699328);    // 768 KB
    unsigned short* xlo    = (unsigned short*)(ws + 10485760);   // 768 KB
    u64*            hS0h   = (u64*)(ws + 11272192);              // 128 KB [128][128]
    u64*            hS0l   = (u64*)(ws + 11403264);              // 128 KB
    u64*            hS1h   = (u64*)(ws + 11534336);              // 128 KB
    u64*            hS1l   = (u64*)(ws + 11665408);              // 128 KB
    unsigned*       bar    = (unsigned*)(ws + 11796480);         // 4 KB flags
    u64*            uPh    = (u64*)(ws + 11800576);              // 2 MB [2048][128]
    u64*            uPl    = (u64*)(ws + 13897728);              // 2 MB
    u64*            hD0h   = (u64*)(ws + 15994880);              // 2 MB
    u64*            hD0l   = (u64*)(ws + 18092032);              // 2 MB
    u64*            hD1h   = (u64*)(ws + 20189184);              // 2 MB
    u64*            hD1l   = (u64*)(ws + 22286336);              // 2 MB

    // zero h(0) encoder state + all flags
    hipMemsetAsync(ws + 11272192, 0, 262144, stream);
    hipMemsetAsync(ws + 11796480, 0, 4096, stream);

    pack_w<<<384, 256, 0, stream>>>(enc_Whh, whh_p, 3 * HD, HD);
    pack_w<<<24, 256, 0, stream>>>(enc_Wih, wih_p, 3 * HD, NI);
    pack_w<<<128, 256, 0, stream>>>(f_W1, w1_p, HD, HD);
    pack_w<<<128, 256, 0, stream>>>(f_W2, w2_p, HD, HD);
    pack_w<<<128, 256, 0, stream>>>(g_W, gw_p, HD, HD);
    pack_w<<<384, 256, 0, stream>>>(dec_Whh, dwhh_p, 3 * HD, HD);
    pack_w<<<8, 256, 0, stream>>>(out_W, outw_p, NI, HD);
    pack_x<<<48, 256, 0, stream>>>(x, xhi, xlo);

    void* args[] = {
        (void*)&xhi, (void*)&xlo, (void*)&wih_p, (void*)&whh_p,
        (void*)&w1_p, (void*)&w2_p, (void*)&gw_p, (void*)&dwhh_p, (void*)&outw_p,
        (void*)&enc_bih, (void*)&enc_bhh, (void*)&f_b1, (void*)&f_b2,
        (void*)&g_b, (void*)&dec_bih, (void*)&dec_bhh, (void*)&out_b,
        (void*)&noise,
        (void*)&hS0h, (void*)&hS0l, (void*)&hS1h, (void*)&hS1l,
        (void*)&uPh, (void*)&uPl, (void*)&hD0h, (void*)&hD0l, (void*)&hD1h, (void*)&hD1l,
        (void*)&out, (void*)&bar
    };
    hipLaunchCooperativeKernel((void*)coop_all, dim3(256), dim3(512), args, 0, stream);
}